// Round 13
// baseline (208.073 us; speedup 1.0000x reference)
//
#include <hip/hip_runtime.h>
#include <math.h>

// N=768 atoms, T=256 tokens, CA=128, CP=16, CZ=128, CS=384, CT=384, H=4, DH=32
// d_out: a_out[256*384]@0, qout[768*384]@98304, c[768*128]@393216, pair[768*768*16]@491520

__device__ __forceinline__ float sigmoidf_(float v) { return 1.f / (1.f + __expf(-v)); }

typedef __attribute__((ext_vector_type(4))) short s16x4;
typedef __attribute__((ext_vector_type(8))) short s16x8;
typedef __attribute__((ext_vector_type(4))) float f32x4;

__device__ __forceinline__ unsigned bfpack(float a, float b) {
  return (__float_as_uint(a) >> 16) | (__float_as_uint(b) & 0xFFFF0000u);
}
__device__ __forceinline__ short bf1(float a) { return (short)(__float_as_uint(a) >> 16); }

// ---------------------------------------------------------------------------
// k_tokatoms: grid 256, block 128
__global__ __launch_bounds__(128) void k_tokatoms(
    const float* __restrict__ s, const float* __restrict__ g,
    const float* __restrict__ b, const float* __restrict__ W_single,
    const float* __restrict__ ref_pos, const float* __restrict__ r,
    const float* __restrict__ W_pos, const float* __restrict__ W_noisy,
    const float* __restrict__ Wca, const float* __restrict__ Wcb,
    float* __restrict__ c_out, float* __restrict__ x,
    float* __restrict__ ca, float* __restrict__ cb) {
  int tok = blockIdx.x, t = threadIdx.x;
  __shared__ float sln[384];
  __shared__ float ws[48 * 128];
  __shared__ float red[4];
  __shared__ float rc[128];
  float v0 = s[tok * 384 + t], v1 = s[tok * 384 + 128 + t], v2 = s[tok * 384 + 256 + t];
  float ps = v0 + v1 + v2, pq = v0 * v0 + v1 * v1 + v2 * v2;
#pragma unroll
  for (int o = 1; o < 64; o <<= 1) { ps += __shfl_xor(ps, o); pq += __shfl_xor(pq, o); }
  if ((t & 63) == 0) { red[t >> 6] = ps; red[2 + (t >> 6)] = pq; }
  __syncthreads();
  float mean = (red[0] + red[1]) * (1.f / 384.f);
  float var = (red[2] + red[3]) * (1.f / 384.f) - mean * mean;
  float rstd = rsqrtf(var + 1e-5f);
  sln[t] = (v0 - mean) * rstd * g[t] + b[t];
  sln[128 + t] = (v1 - mean) * rstd * g[128 + t] + b[128 + t];
  sln[256 + t] = (v2 - mean) * rstd * g[256 + t] + b[256 + t];
  float ctv = 0.f;
  for (int c0 = 0; c0 < 384; c0 += 48) {
    __syncthreads();
#pragma unroll
    for (int m = 0; m < 12; m++) {
      int idx = (t + 128 * m) * 4;
      *(float4*)&ws[idx] = *(const float4*)&W_single[c0 * 128 + idx];
    }
    __syncthreads();
#pragma unroll 8
    for (int kk = 0; kk < 48; kk++) ctv += sln[c0 + kk] * ws[kk * 128 + t];
  }
  float wp0 = W_pos[t], wp1 = W_pos[128 + t], wp2 = W_pos[256 + t];
  float wn0 = W_noisy[t], wn1 = W_noisy[128 + t], wn2 = W_noisy[256 + t];
#pragma unroll
  for (int a = 0; a < 3; a++) {
    int i = tok + 256 * a;
    float p0 = ref_pos[i * 3], p1 = ref_pos[i * 3 + 1], p2 = ref_pos[i * 3 + 2];
    float r0 = r[i * 3], r1 = r[i * 3 + 1], r2 = r[i * 3 + 2];
    float c0 = p0 * wp0 + p1 * wp1 + p2 * wp2;
    x[i * 128 + t] = c0 + r0 * wn0 + r1 * wn1 + r2 * wn2;
    float cc = c0 + ctv;
    c_out[i * 128 + t] = cc;
    __syncthreads();
    rc[t] = fmaxf(cc, 0.f);
    __syncthreads();
    int out_id = t >> 2, q = t & 3;
    const float* Wm = (out_id < 16) ? Wca : Wcb;
    int ch = out_id & 15;
    float acc = 0.f;
#pragma unroll
    for (int kk = 0; kk < 32; kk++) { int k = q * 32 + kk; acc += rc[k] * Wm[k * 16 + ch]; }
    acc += __shfl_xor(acc, 1);
    acc += __shfl_xor(acc, 2);
    if (q == 0) { if (out_id < 16) ca[i * 16 + ch] = acc; else cb[i * 16 + ch] = acc; }
  }
}

// ---------------------------------------------------------------------------
// k_zp: zp[65536,16] = LN(z)@W_pair   grid 4096, block 256
__global__ __launch_bounds__(256) void k_zp(
    const float* __restrict__ z, const float* __restrict__ g,
    const float* __restrict__ lb, const float* __restrict__ W_pair,
    float* __restrict__ zp) {
  __shared__ float wT[16][132];
  __shared__ float zs[16][132];
  __shared__ float sWg[16], Bc[16];
  int t = threadIdx.x;
#pragma unroll
  for (int m = 0; m < 8; m++) {
    int e = t + 256 * m;
    int row = e >> 4, ch = e & 15;
    wT[ch][row] = g[row] * W_pair[e];
  }
  __syncthreads();
  if (t < 32) {
    int ch = t & 15;
    float a = 0.f;
    if (t < 16) {
#pragma unroll 8
      for (int k = 0; k < 128; k++) a += wT[ch][k];
      sWg[ch] = a;
    } else {
#pragma unroll 8
      for (int k = 0; k < 128; k++) a += lb[k] * W_pair[k * 16 + ch];
      Bc[ch] = a;
    }
  }
  int row = t >> 4, kk = (t & 15) * 8;
  long base = ((long)blockIdx.x * 16 + row) * 128 + kk;
  float4 a4 = *(const float4*)&z[base];
  float4 b4 = *(const float4*)&z[base + 4];
  *(float4*)&zs[row][kk] = a4;
  *(float4*)&zs[row][kk + 4] = b4;
  float ps = a4.x + a4.y + a4.z + a4.w + b4.x + b4.y + b4.z + b4.w;
  float pq = a4.x * a4.x + a4.y * a4.y + a4.z * a4.z + a4.w * a4.w +
             b4.x * b4.x + b4.y * b4.y + b4.z * b4.z + b4.w * b4.w;
#pragma unroll
  for (int o = 1; o < 16; o <<= 1) { ps += __shfl_xor(ps, o); pq += __shfl_xor(pq, o); }
  float m = ps * (1.f / 128.f);
  float rstd = rsqrtf(pq * (1.f / 128.f) - m * m + 1e-5f);
  __syncthreads();
  int ch = t & 15;
  float dotv = 0.f;
#pragma unroll 8
  for (int k4 = 0; k4 < 32; k4++) {
    float4 zv = *(float4*)&zs[row][k4 * 4];
    float4 wv = *(float4*)&wT[ch][k4 * 4];
    dotv += zv.x * wv.x + zv.y * wv.y + zv.z * wv.z + zv.w * wv.w;
  }
  zp[((long)blockIdx.x * 16 + row) * 16 + ch] = rstd * (dotv - m * sWg[ch]) + Bc[ch];
}

// ---------------------------------------------------------------------------
// k_pairM: pair + MFMA MLP + fused window bias.  grid 2304, block 256
__global__ __launch_bounds__(256) void k_pairM(
    const float* __restrict__ ref_pos, const int* __restrict__ uid,
    const float* __restrict__ Wpo, const float* __restrict__ Wisd,
    const float* __restrict__ Wmask, const float* __restrict__ W1,
    const float* __restrict__ W2, const float* __restrict__ W3,
    const float* __restrict__ zp, const float* __restrict__ ca,
    const float* __restrict__ cb, const float* __restrict__ lnp_g,
    const float* __restrict__ lnp_b, const float* __restrict__ Wb,
    float* __restrict__ pair_out, float* __restrict__ biasA) {
  int i = blockIdx.x / 3, jb = blockIdx.x % 3, t = threadIdx.x;
  __shared__ float jsx[256], jsy[256], jsz[256];
  __shared__ int jsu[256];
  __shared__ __align__(128) short stg[4][1280];
  __shared__ __align__(16) float pfs[4][1056];
  __shared__ float wgb[192];
  __shared__ float kbs[12];
  int jg = jb * 256 + t;
  jsx[t] = ref_pos[jg * 3];
  jsy[t] = ref_pos[jg * 3 + 1];
  jsz[t] = ref_pos[jg * 3 + 2];
  jsu[t] = uid[jg];
  if (t >= 64) {
    int e = t - 64;
    if (e < 192) {
      int bq = e >> 6, k = (e >> 2) & 15, h = e & 3;
      wgb[e] = lnp_g[bq * 16 + k] * Wb[bq * 64 + k * 4 + h];
    }
  }
  if (t >= 48 && t < 60) {
    int e = t - 48, bq = e >> 2, h = e & 3;
    float a = 0.f;
#pragma unroll
    for (int cc = 0; cc < 16; cc++) a += lnp_b[bq * 16 + cc] * Wb[bq * 64 + cc * 4 + h];
    kbs[e] = a;
  }
  int w = t >> 6, l = t & 63;
  int c = l & 15, gr = l >> 4;
  float pix = ref_pos[i * 3], piy = ref_pos[i * 3 + 1], piz = ref_pos[i * 3 + 2];
  int ui = uid[i];
  float w0c = Wpo[c], w1c = Wpo[16 + c], w2c = Wpo[32 + c];
  float wic = Wisd[c], wmc = Wmask[c], cac = ca[i * 16 + c];
  s16x8 bw0 = {bf1(W1[(4 * gr + 0) * 16 + c]), bf1(W1[(4 * gr + 1) * 16 + c]),
               bf1(W1[(4 * gr + 2) * 16 + c]), bf1(W1[(4 * gr + 3) * 16 + c]),
               (short)0, (short)0, (short)0, (short)0};
  s16x8 bw1 = {bf1(W2[(4 * gr + 0) * 16 + c]), bf1(W2[(4 * gr + 1) * 16 + c]),
               bf1(W2[(4 * gr + 2) * 16 + c]), bf1(W2[(4 * gr + 3) * 16 + c]),
               (short)0, (short)0, (short)0, (short)0};
  s16x8 bw2 = {bf1(W3[(4 * gr + 0) * 16 + c]), bf1(W3[(4 * gr + 1) * 16 + c]),
               bf1(W3[(4 * gr + 2) * 16 + c]), bf1(W3[(4 * gr + 3) * 16 + c]),
               (short)0, (short)0, (short)0, (short)0};
  __syncthreads();
  char* sb = (char*)&stg[w][0];
  unsigned sbase = (unsigned)(uintptr_t)sb;
  f32x4 z4 = {0.f, 0.f, 0.f, 0.f};
#pragma unroll
  for (int g = 0; g < 4; g++) {
    float p0_, p1_, p2_, p3_;
    {
      int jl0 = w * 64 + g * 16 + 4 * gr;
#pragma unroll
      for (int r = 0; r < 4; r++) {
        int jloc = jl0 + r;
        int j = jb * 256 + jloc;
        float d0 = pix - jsx[jloc], d1 = piy - jsy[jloc], d2 = piz - jsz[jloc];
        float mk = (ui == jsu[jloc]) ? 1.f : 0.f;
        float inv = 1.f / (1.f + d0 * d0 + d1 * d1 + d2 * d2);
        float zv = zp[((long)((i & 255) << 8) + jloc) * 16 + c];
        float cbv = cb[j * 16 + c];
        float pv = mk * (d0 * w0c + d1 * w1c + d2 * w2c + inv * wic + wmc) + zv + cbv + cac;
        if (r == 0) p0_ = pv; else if (r == 1) p1_ = pv; else if (r == 2) p2_ = pv; else p3_ = pv;
      }
    }
    char* wp = sb + g * 640 + c * 32 + gr * 8;
    unsigned ra = sbase + (unsigned)(g * 640 + c * 8 + gr * 128);
    *(uint2*)wp = make_uint2(bfpack(fmaxf(p0_, 0.f), fmaxf(p1_, 0.f)),
                             bfpack(fmaxf(p2_, 0.f), fmaxf(p3_, 0.f)));
    s16x4 tr0;
    asm volatile("s_waitcnt lgkmcnt(0)\n\tds_read_b64_tr_b16 %0, %1\n\ts_waitcnt lgkmcnt(0)"
                 : "=v"(tr0) : "v"(ra) : "memory");
    s16x8 a8 = {tr0[0], tr0[1], tr0[2], tr0[3], (short)0, (short)0, (short)0, (short)0};
    f32x4 h1 = __builtin_amdgcn_mfma_f32_16x16x32_bf16(a8, bw0, z4, 0, 0, 0);
    *(uint2*)wp = make_uint2(bfpack(fmaxf(h1[0], 0.f), fmaxf(h1[1], 0.f)),
                             bfpack(fmaxf(h1[2], 0.f), fmaxf(h1[3], 0.f)));
    s16x4 tr1;
    asm volatile("s_waitcnt lgkmcnt(0)\n\tds_read_b64_tr_b16 %0, %1\n\ts_waitcnt lgkmcnt(0)"
                 : "=v"(tr1) : "v"(ra) : "memory");
    s16x8 a8b = {tr1[0], tr1[1], tr1[2], tr1[3], (short)0, (short)0, (short)0, (short)0};
    f32x4 h2 = __builtin_amdgcn_mfma_f32_16x16x32_bf16(a8b, bw1, z4, 0, 0, 0);
    *(uint2*)wp = make_uint2(bfpack(fmaxf(h2[0], 0.f), fmaxf(h2[1], 0.f)),
                             bfpack(fmaxf(h2[2], 0.f), fmaxf(h2[3], 0.f)));
    s16x4 tr2;
    asm volatile("s_waitcnt lgkmcnt(0)\n\tds_read_b64_tr_b16 %0, %1\n\ts_waitcnt lgkmcnt(0)"
                 : "=v"(tr2) : "v"(ra) : "memory");
    s16x8 a8c = {tr2[0], tr2[1], tr2[2], tr2[3], (short)0, (short)0, (short)0, (short)0};
    f32x4 h3 = __builtin_amdgcn_mfma_f32_16x16x32_bf16(a8c, bw2, z4, 0, 0, 0);
    float f0 = p0_ + h3[0], f1 = p1_ + h3[1], f2 = p2_ + h3[2], f3 = p3_ + h3[3];
    {
      int jl0 = w * 64 + g * 16 + 4 * gr;
      long pb = ((long)i * 768 + (long)(jb * 256 + jl0)) * 16 + c;
      pair_out[pb] = f0;
      pair_out[pb + 16] = f1;
      pair_out[pb + 32] = f2;
      pair_out[pb + 48] = f3;
    }
    *(float4*)&pfs[w][g * 264 + c * 16 + 4 * gr] = make_float4(f0, f1, f2, f3);
  }
  asm volatile("s_waitcnt lgkmcnt(0)" ::: "memory");
  int qb = i >> 5;
  int j = jb * 256 + t;
  unsigned jw = (unsigned)(j - (qb * 32 - 48));
  if (jw < 128u) {
    int gt = (t >> 4) & 3, jr = t & 15;
    float v[16];
#pragma unroll
    for (int cc = 0; cc < 16; cc++) v[cc] = pfs[w][gt * 264 + cc * 16 + jr];
    float m = 0.f;
#pragma unroll
    for (int cc = 0; cc < 16; cc++) m += v[cc];
    m *= (1.f / 16.f);
    float vv = 0.f;
#pragma unroll
    for (int cc = 0; cc < 16; cc++) { float d = v[cc] - m; vv += d * d; }
    float rs = rsqrtf(vv * (1.f / 16.f) + 1e-5f);
    float nrm[16];
#pragma unroll
    for (int cc = 0; cc < 16; cc++) nrm[cc] = (v[cc] - m) * rs;
    int qi = i & 31;
#pragma unroll
    for (int bq = 0; bq < 3; bq++) {
      float o0 = kbs[bq * 4 + 0], o1 = kbs[bq * 4 + 1];
      float o2 = kbs[bq * 4 + 2], o3 = kbs[bq * 4 + 3];
#pragma unroll
      for (int k = 0; k < 16; k++) {
        float nv = nrm[k];
        float4 wv = *(float4*)&wgb[bq * 64 + k * 4];
        o0 += nv * wv.x; o1 += nv * wv.y; o2 += nv * wv.z; o3 += nv * wv.w;
      }
      long base = (long)(bq * 96 + qb * 4) * 4096 + (long)qi * 128 + jw;
      biasA[base] = o0;
      biasA[base + 4096] = o1;
      biasA[base + 2 * 4096] = o2;
      biasA[base + 3 * 4096] = o3;
    }
  }
}

// ---------------------------------------------------------------------------
// k_qkvg (layer 0 only): grid 384 (rb*8+bn), block 256
__global__ __launch_bounds__(256) void k_qkvg(
    const float* __restrict__ x, const float* __restrict__ lng,
    const float* __restrict__ lnb, const float* __restrict__ Wq,
    const float* __restrict__ Wk, const float* __restrict__ Wv,
    const float* __restrict__ Wg, float* __restrict__ qkvg) {
  __shared__ float As[128][18];
  __shared__ float Ws[128][66];
  int t = threadIdx.x;
  int rb = blockIdx.x >> 3, bn = blockIdx.x & 7;
  int r0 = rb * 16;
  const float* Wm = (bn < 2) ? Wq : (bn < 4) ? Wk : (bn < 6) ? Wv : Wg;
  int c0 = (bn & 1) * 64;
  int ncol0 = (bn >> 1) * 128 + c0;
#pragma unroll
  for (int m = 0; m < 8; m++) {
    int idx = t + 256 * m;
    int row = idx >> 4, c4 = (idx & 15) * 4;
    *(float4*)&Ws[row][c4] = *(const float4*)&Wm[row * 128 + c0 + c4];
  }
  {
    int rr = t >> 4, tt = t & 15;
    int row = r0 + rr;
    float4 x0 = *(const float4*)&x[row * 128 + tt * 8];
    float4 x1 = *(const float4*)&x[row * 128 + tt * 8 + 4];
    float ps = x0.x + x0.y + x0.z + x0.w + x1.x + x1.y + x1.z + x1.w;
    float pq = x0.x * x0.x + x0.y * x0.y + x0.z * x0.z + x0.w * x0.w +
               x1.x * x1.x + x1.y * x1.y + x1.z * x1.z + x1.w * x1.w;
#pragma unroll
    for (int o = 1; o < 16; o <<= 1) { ps += __shfl_xor(ps, o); pq += __shfl_xor(pq, o); }
    float m = ps * (1.f / 128.f);
    float rstd = rsqrtf(pq * (1.f / 128.f) - m * m + 1e-5f);
    float4 g0 = *(const float4*)&lng[tt * 8], g1 = *(const float4*)&lng[tt * 8 + 4];
    float4 b0 = *(const float4*)&lnb[tt * 8], b1 = *(const float4*)&lnb[tt * 8 + 4];
    As[tt * 8 + 0][rr] = (x0.x - m) * rstd * g0.x + b0.x;
    As[tt * 8 + 1][rr] = (x0.y - m) * rstd * g0.y + b0.y;
    As[tt * 8 + 2][rr] = (x0.z - m) * rstd * g0.z + b0.z;
    As[tt * 8 + 3][rr] = (x0.w - m) * rstd * g0.w + b0.w;
    As[tt * 8 + 4][rr] = (x1.x - m) * rstd * g1.x + b1.x;
    As[tt * 8 + 5][rr] = (x1.y - m) * rstd * g1.y + b1.y;
    As[tt * 8 + 6][rr] = (x1.z - m) * rstd * g1.z + b1.z;
    As[tt * 8 + 7][rr] = (x1.w - m) * rstd * g1.w + b1.w;
  }
  __syncthreads();
  int ty = t >> 5, tx = t & 31;
  float a00 = 0, a01 = 0, a10 = 0, a11 = 0;
#pragma unroll 8
  for (int k = 0; k < 128; k++) {
    float2 a2 = *(float2*)&As[k][ty * 2];
    float2 w2 = *(float2*)&Ws[k][tx * 2];
    a00 += a2.x * w2.x; a01 += a2.x * w2.y;
    a10 += a2.y * w2.x; a11 += a2.y * w2.y;
  }
  int row = r0 + ty * 2;
  float2 o0 = {a00, a01}, o1 = {a10, a11};
  *(float2*)&qkvg[row * 512 + ncol0 + tx * 2] = o0;
  *(float2*)&qkvg[(row + 1) * 512 + ncol0 + tx * 2] = o1;
}

// ---------------------------------------------------------------------------
// k_attn2: windowed attention, 16-row q-tiles.  grid 192 (qt*4+h), block 256
__global__ __launch_bounds__(256) void k_attn2(
    const float* __restrict__ qkvg, const float* __restrict__ biasb,
    float* __restrict__ og) {
  int qt = blockIdx.x >> 2, h = blockIdx.x & 3, t = threadIdx.x;
  int i0 = qt * 16;
  int qb32 = qt >> 1;
  int lo = qb32 * 32 - 48;
  int qoff = (qt & 1) * 16;
  __shared__ float qs[16][36];
  __shared__ float ks[128][36];
  __shared__ float vs[128][36];
  __shared__ float L[16][132];
  // bias -> L (16x128), 8 floats per thread
  {
    int e = t * 8;
    int qi = e >> 7, k8 = e & 127;
    const float* bb = &biasb[(long)(qb32 * 4 + h) * 4096 + (long)(qoff + qi) * 128];
#pragma unroll
    for (int m = 0; m < 2; m++) {
      int k4 = k8 + m * 4;
      int j4 = lo + k4;
      float4 bv;
      if (j4 >= 0 && j4 <= 764) bv = *(const float4*)&bb[k4];
      else bv = make_float4(-1e30f, -1e30f, -1e30f, -1e30f);
      *(float4*)&L[qi][k4] = bv;
    }
  }
  // Q (16 rows x 32) : threads 0..127
  if (t < 128) {
    int qi = t >> 3, dq = (t & 7) * 4;
    *(float4*)&qs[qi][dq] = *(const float4*)&qkvg[(i0 + qi) * 512 + h * 32 + dq];
  }
  // K/V window
  {
    int kj = t >> 1, dh = (t & 1) * 16;
    int j = lo + kj;
    if (j >= 0 && j < 768) {
      const float4* sk = (const float4*)&qkvg[j * 512 + 128 + h * 32 + dh];
      const float4* sv = (const float4*)&qkvg[j * 512 + 256 + h * 32 + dh];
#pragma unroll
      for (int m = 0; m < 4; m++) {
        *(float4*)&ks[kj][dh + 4 * m] = sk[m];
        *(float4*)&vs[kj][dh + 4 * m] = sv[m];
      }
    } else {
      float4 zz = {0, 0, 0, 0};
#pragma unroll
      for (int m = 0; m < 4; m++) {
        *(float4*)&ks[kj][dh + 4 * m] = zz;
        *(float4*)&vs[kj][dh + 4 * m] = zz;
      }
    }
  }
  __syncthreads();
  const float scale = 0.17677669529663687f;
  // QK^T: thread (qi = t&15, kb = t>>4), 8 kj each
  {
    int qi = t & 15, kb = t >> 4;
    float4 qr[8];
#pragma unroll
    for (int m = 0; m < 8; m++) qr[m] = *(float4*)&qs[qi][m * 4];
#pragma unroll
    for (int kk = 0; kk < 8; kk++) {
      int kj = kb * 8 + kk;
      float acc = 0.f;
#pragma unroll
      for (int m = 0; m < 8; m++) {
        float4 kv = *(float4*)&ks[kj][m * 4];
        acc += qr[m].x * kv.x + qr[m].y * kv.y + qr[m].z * kv.z + qr[m].w * kv.w;
      }
      L[qi][kj] += acc * scale;
    }
  }
  __syncthreads();
  // softmax: 16 threads per row (qi = t>>4, sg = t&15), 8 cols each
  int qi = t >> 4, sg = t & 15;
  float mx = -1e30f;
#pragma unroll
  for (int k2 = 0; k2 < 8; k2++) mx = fmaxf(mx, L[qi][sg * 8 + k2]);
#pragma unroll
  for (int o = 1; o < 16; o <<= 1) mx = fmaxf(mx, __shfl_xor(mx, o));
  float sum = 0.f;
#pragma unroll
  for (int k2 = 0; k2 < 8; k2++) {
    int kj = sg * 8 + k2;
    float e = __expf(L[qi][kj] - mx);
    L[qi][kj] = e;
    sum += e;
  }
#pragma unroll
  for (int o = 1; o < 16; o <<= 1) sum += __shfl_xor(sum, o);
  float rden = 1.f / sum;
  __syncthreads();
  // PV: thread (qi = t>>4, d2 = (t&15)*2)
  {
    int d2 = (t & 15) * 2;
    float a0 = 0.f, a1 = 0.f;
#pragma unroll 8
    for (int kj = 0; kj < 128; kj++) {
      float p = L[qi][kj];
      float2 v = *(float2*)&vs[kj][d2];
      a0 += p * v.x; a1 += p * v.y;
    }
    int i = i0 + qi;
    float2 gr = *(const float2*)&qkvg[i * 512 + 384 + h * 32 + d2];
    float2 o2;
    o2.x = a0 * rden * sigmoidf_(gr.x);
    o2.y = a1 * rden * sigmoidf_(gr.y);
    *(float2*)&og[i * 128 + h * 32 + d2] = o2;
  }
}

// ---------------------------------------------------------------------------
// k_fusedT<MODE>: x += og@Wo; a=LN(x); x += relu(a@Wt1)@Wt2; then
//  MODE 1: qkvg_next = LN_next(x) @ [Wq|Wk|Wv|Wg]
//  MODE 2: qout = relu(x@W_proj), a_out = mean (k_final fused)
// grid 256 (3 rows/block, 1/CU), block 384.
template <int MODE>
__global__ __launch_bounds__(384) void k_fusedT(
    const float* __restrict__ og, const float* __restrict__ Wo,
    const float* __restrict__ g2, const float* __restrict__ b2,
    const float* __restrict__ Wt1, const float* __restrict__ Wt2,
    float* __restrict__ x,
    const float* __restrict__ lng_n, const float* __restrict__ lnb_n,
    const float* __restrict__ Wq, const float* __restrict__ Wk,
    const float* __restrict__ Wv, const float* __restrict__ Wg,
    float* __restrict__ qkvg, const float* __restrict__ W_proj,
    float* __restrict__ out) {
  int t = threadIdx.x;
  int r0 = blockIdx.x * 3;
  __shared__ float osr[3][128];
  __shared__ float xns[3][128];
  __shared__ float asr[3][128];
  __shared__ float hs[3][512];
  __shared__ float part[4][3][128];
  __shared__ float red[12];
  {
    int rr = t >> 7, c = t & 127;
    osr[rr][c] = og[(r0 + rr) * 128 + c];
    xns[rr][c] = x[(r0 + rr) * 128 + c];
  }
  __syncthreads();
  // ---- GEMM1 (k-split 4) ----
  {
    int c4 = (t & 31) * 4, row = (t >> 5) % 3, q = t / 96;
    int k0 = q * 32;
    float a0 = 0.f, a1 = 0.f, a2 = 0.f, a3 = 0.f;
#pragma unroll 16
    for (int kk = 0; kk < 32; kk++) {
      int k = k0 + kk;
      float4 w = *(const float4*)&Wo[k * 128 + c4];
      float av = osr[row][k];
      a0 += av * w.x; a1 += av * w.y; a2 += av * w.z; a3 += av * w.w;
    }
    *(float4*)&part[q][row][c4] = make_float4(a0, a1, a2, a3);
  }
  __syncthreads();
  // ---- combine + LN ----
  {
    int rr = t >> 7, c = t & 127;
    float xv = xns[rr][c] + part[0][rr][c] + part[1][rr][c] + part[2][rr][c] + part[3][rr][c];
    float ps = xv, pq = xv * xv;
#pragma unroll
    for (int o = 1; o < 64; o <<= 1) { ps += __shfl_xor(ps, o); pq += __shfl_xor(pq, o); }
    int wv = t >> 6;
    if ((t & 63) == 0) { red[wv] = ps; red[6 + wv] = pq; }
    __syncthreads();
    float mean = (red[2 * rr] + red[2 * rr + 1]) * (1.f / 128.f);
    float var = (red[6 + 2 * rr] + red[6 + 2 * rr + 1]) * (1.f / 128.f) - mean * mean;
    float rstd = rsqrtf(var + 1e-5f);
    xns[rr][c] = xv;
    asr[rr][c] = (xv - mean) * rstd * g2[c] + b2[c];
  }
  __syncthreads();
  // ---- GEMM2: hs = relu(asr @ Wt1) ----
  {
    int c4 = (t & 127) * 4, row = t >> 7;
    float a0 = 0.f, a1 = 0.f, a2 = 0.f, a3 = 0.f;
#pragma unroll 16
    for (int k = 0; k < 128; k++) {
      float4 w = *(const float4*)&Wt1[k * 512 + c4];
      float av = asr[row][k];
      a0 += av * w.x; a1 += av * w.y; a2 += av * w.z; a3 += av * w.w;
    }
    *(float4*)&hs[row][c4] = make_float4(fmaxf(a0, 0.f), fmaxf(a1, 0.f),
                                         fmaxf(a2, 0.f), fmaxf(a3, 0.f));
  }
  __syncthreads();
  // ---- GEMM3 (k-split 4) ----
  {
    int c4 = (t & 31) * 4, row = (t >> 5) % 3, q = t / 96;
    int k0 = q * 128;
    float a0 = 0.f, a1 = 0.f, a2 = 0.f, a3 = 0.f;
#pragma unroll 16
    for (int kk = 0; kk < 128; kk++) {
      int k = k0 + kk;
      float4 w = *(const float4*)&Wt2[k * 128 + c4];
      float hv = hs[row][k];
      a0 += hv * w.x; a1 += hv * w.y; a2 += hv * w.z; a3 += hv * w.w;
    }
    *(float4*)&part[q][row][c4] = make_float4(a0, a1, a2, a3);
  }
  __syncthreads();
  // ---- final x + optional fused tails ----
  {
    int rr = t >> 7, c = t & 127;
    float xf = xns[rr][c] + part[0][rr][c] + part[1][rr][c] +
               part[2][rr][c] + part[3][rr][c];
    x[(r0 + rr) * 128 + c] = xf;
    xns[rr][c] = xf;
  }
  if (MODE == 1) {
    __syncthreads();
    {
      int rr = t >> 7, c = t & 127;
      float xv = xns[rr][c];
      float ps = xv, pq = xv * xv;
#pragma unroll
      for (int o = 1; o < 64; o <<= 1) { ps += __shfl_xor(ps, o); pq += __shfl_xor(pq, o); }
      int wv = t >> 6;
      if ((t & 63) == 0) { red[wv] = ps; red[6 + wv] = pq; }
      __syncthreads();
      float mean = (red[2 * rr] + red[2 * rr + 1]) * (1.f / 128.f);
      float var = (red[6 + 2 * rr] + red[6 + 2 * rr + 1]) * (1.f / 128.f) - mean * mean;
      float rstd = rsqrtf(var + 1e-5f);
      asr[rr][c] = (xv - mean) * rstd * lng_n[c] + lnb_n[c];
    }
    __syncthreads();
    {
      int c4 = (t & 127) * 4, row = t >> 7;
      int mtx = c4 >> 7, lc = c4 & 127;
      const float* Wm = (mtx == 0) ? Wq : (mtx == 1) ? Wk : (mtx == 2) ? Wv : Wg;
      float a0 = 0.f, a1 = 0.f, a2 = 0.f, a3 = 0.f;
#pragma unroll 16
      for (int k = 0; k < 128; k++) {
        float4 w = *(const float4*)&Wm[k * 128 + lc];
        float av = asr[row][k];
        a0 += av * w.x; a1 += av * w.y; a2 += av * w.z; a3 += av * w.w;
      }
      *(float4*)&qkvg[(r0 + row) * 512 + c4] = make_float4(a0, a1, a2, a3);
    }
  }
  if (MODE == 2) {
    __syncthreads();
    int tk = blockIdx.x;
    float a0 = 0.f, a1 = 0.f, a2 = 0.f;
#pragma unroll 8
    for (int k = 0; k < 128; k++) {
      float w = W_proj[k * 384 + t];
      a0 += xns[0][k] * w; a1 += xns[1][k] * w; a2 += xns[2][k] * w;
    }
    a0 = fmaxf(a0, 0.f); a1 = fmaxf(a1, 0.f); a2 = fmaxf(a2, 0.f);
    out[98304 + (tk * 3 + 0) * 384 + t] = a0;
    out[98304 + (tk * 3 + 1) * 384 + t] = a1;
    out[98304 + (tk * 3 + 2) * 384 + t] = a2;
    out[tk * 384 + t] = (a0 + a1 + a2) * (1.f / 3.f);
  }
}

// ---------------------------------------------------------------------------
extern "C" void kernel_launch(void* const* d_in, const int* in_sizes, int n_in,
                              void* d_out, int out_size, void* d_ws, size_t ws_size,
                              hipStream_t stream) {
  const float* ref_pos  = (const float*)d_in[0];
  const int*   uid      = (const int*)d_in[1];
  const float* r        = (const float*)d_in[2];
  const float* s        = (const float*)d_in[3];
  const float* z        = (const float*)d_in[4];
  const float* W_pos    = (const float*)d_in[5];
  const float* Wpo      = (const float*)d_in[6];
  const float* Wisd     = (const float*)d_in[7];
  const float* Wmask    = (const float*)d_in[8];
  const float* Wca      = (const float*)d_in[9];
  const float* Wcb      = (const float*)d_in[10];
  const float* ln_s_g   = (const float*)d_in[11];
  const float* ln_s_b   = (const float*)d_in[12];
  const float* W_single = (const float*)d_in[13];
  const float* ln_z_g   = (const float*)d_in[14];
  const float* ln_z_b   = (const float*)d_in[15];
  const float* W_pair   = (const float*)d_in[16];
  const float* W_noisy  = (const float*)d_in[17];
  const float* W_mlp1   = (const float*)d_in[18];
  const float* W_mlp2   = (const float*)d_in[19];
  const float* W_mlp3   = (const float*)d_in[20];
  const float* at_ln_g  = (const float*)d_in[21];
  const float* at_ln_b  = (const float*)d_in[22];
  const float* at_Wq    = (const float*)d_in[23];
  const float* at_Wk    = (const float*)d_in[24];
  const float* at_Wv    = (const float*)d_in[25];
  const float* at_Wg    = (const float*)d_in[26];
  const float* at_lnp_g = (const float*)d_in[27];
  const float* at_lnp_b = (const float*)d_in[28];
  const float* at_Wb    = (const float*)d_in[29];
  const float* at_Wo    = (const float*)d_in[30];
  const float* at_ln2_g = (const float*)d_in[31];
  const float* at_ln2_b = (const float*)d_in[32];
  const float* at_Wt1   = (const float*)d_in[33];
  const float* at_Wt2   = (const float*)d_in[34];
  const float* W_proj   = (const float*)d_in[35];
  float* out = (float*)d_out;
  float* W = (float*)d_ws;
  float* x     = W;                 //   98304
  float* ca    = W + 98304;         //   12288
  float* cb    = W + 110592;        //   12288
  float* zp    = W + 122880;        // 1048576
  float* biasA = W + 1171456;       // 1179648
  float* qkvg  = W + 2351104;       //  393216
  float* og    = W + 2744320;       //   98304

  k_zp<<<4096, 256, 0, stream>>>(z, ln_z_g, ln_z_b, W_pair, zp);
  k_tokatoms<<<256, 128, 0, stream>>>(s, ln_s_g, ln_s_b, W_single, ref_pos, r,
                                      W_pos, W_noisy, Wca, Wcb,
                                      out + 393216, x, ca, cb);
  k_pairM<<<2304, 256, 0, stream>>>(ref_pos, uid, Wpo, Wisd, Wmask, W_mlp1, W_mlp2,
                                    W_mlp3, zp, ca, cb, at_lnp_g, at_lnp_b, at_Wb,
                                    out + 491520, biasA);
  k_qkvg<<<384, 256, 0, stream>>>(x, at_ln_g, at_ln_b, at_Wq, at_Wk, at_Wv, at_Wg, qkvg);
  // layer 0
  k_attn2<<<192, 256, 0, stream>>>(qkvg, biasA, og);
  k_fusedT<1><<<256, 384, 0, stream>>>(og, at_Wo, at_ln2_g, at_ln2_b, at_Wt1, at_Wt2, x,
                                       at_ln_g + 128, at_ln_b + 128,
                                       at_Wq + 16384, at_Wk + 16384,
                                       at_Wv + 16384, at_Wg + 16384, qkvg,
                                       nullptr, nullptr);
  // layer 1
  k_attn2<<<192, 256, 0, stream>>>(qkvg, biasA + 393216, og);
  k_fusedT<1><<<256, 384, 0, stream>>>(og, at_Wo + 16384, at_ln2_g + 128, at_ln2_b + 128,
                                       at_Wt1 + 65536, at_Wt2 + 65536, x,
                                       at_ln_g + 256, at_ln_b + 256,
                                       at_Wq + 32768, at_Wk + 32768,
                                       at_Wv + 32768, at_Wg + 32768, qkvg,
                                       nullptr, nullptr);
  // layer 2
  k_attn2<<<192, 256, 0, stream>>>(qkvg, biasA + 786432, og);
  k_fusedT<2><<<256, 384, 0, stream>>>(og, at_Wo + 32768, at_ln2_g + 256, at_ln2_b + 256,
                                       at_Wt1 + 131072, at_Wt2 + 131072, x,
                                       nullptr, nullptr, nullptr, nullptr,
                                       nullptr, nullptr, nullptr, W_proj, out);
}

// Round 14
// 158.413 us; speedup vs baseline: 1.3135x; 1.3135x over previous
//
#include <hip/hip_runtime.h>
#include <math.h>

// N=768 atoms, T=256 tokens, CA=128, CP=16, CZ=128, CS=384, CT=384, H=4, DH=32
// d_out: a_out[256*384]@0, qout[768*384]@98304, c[768*128]@393216, pair[768*768*16]@491520

__device__ __forceinline__ float sigmoidf_(float v) { return 1.f / (1.f + __expf(-v)); }

typedef __attribute__((ext_vector_type(4))) short s16x4;
typedef __attribute__((ext_vector_type(8))) short s16x8;
typedef __attribute__((ext_vector_type(4))) float f32x4;

__device__ __forceinline__ unsigned bfpack(float a, float b) {
  return (__float_as_uint(a) >> 16) | (__float_as_uint(b) & 0xFFFF0000u);
}
__device__ __forceinline__ short bf1(float a) { return (short)(__float_as_uint(a) >> 16); }

// ---------------------------------------------------------------------------
// k_tokatoms: grid 256, block 128
__global__ __launch_bounds__(128) void k_tokatoms(
    const float* __restrict__ s, const float* __restrict__ g,
    const float* __restrict__ b, const float* __restrict__ W_single,
    const float* __restrict__ ref_pos, const float* __restrict__ r,
    const float* __restrict__ W_pos, const float* __restrict__ W_noisy,
    const float* __restrict__ Wca, const float* __restrict__ Wcb,
    float* __restrict__ c_out, float* __restrict__ x,
    float* __restrict__ ca, float* __restrict__ cb) {
  int tok = blockIdx.x, t = threadIdx.x;
  __shared__ float sln[384];
  __shared__ float ws[48 * 128];
  __shared__ float red[4];
  __shared__ float rc[128];
  float v0 = s[tok * 384 + t], v1 = s[tok * 384 + 128 + t], v2 = s[tok * 384 + 256 + t];
  float ps = v0 + v1 + v2, pq = v0 * v0 + v1 * v1 + v2 * v2;
#pragma unroll
  for (int o = 1; o < 64; o <<= 1) { ps += __shfl_xor(ps, o); pq += __shfl_xor(pq, o); }
  if ((t & 63) == 0) { red[t >> 6] = ps; red[2 + (t >> 6)] = pq; }
  __syncthreads();
  float mean = (red[0] + red[1]) * (1.f / 384.f);
  float var = (red[2] + red[3]) * (1.f / 384.f) - mean * mean;
  float rstd = rsqrtf(var + 1e-5f);
  sln[t] = (v0 - mean) * rstd * g[t] + b[t];
  sln[128 + t] = (v1 - mean) * rstd * g[128 + t] + b[128 + t];
  sln[256 + t] = (v2 - mean) * rstd * g[256 + t] + b[256 + t];
  float ctv = 0.f;
  for (int c0 = 0; c0 < 384; c0 += 48) {
    __syncthreads();
#pragma unroll
    for (int m = 0; m < 12; m++) {
      int idx = (t + 128 * m) * 4;
      *(float4*)&ws[idx] = *(const float4*)&W_single[c0 * 128 + idx];
    }
    __syncthreads();
#pragma unroll 8
    for (int kk = 0; kk < 48; kk++) ctv += sln[c0 + kk] * ws[kk * 128 + t];
  }
  float wp0 = W_pos[t], wp1 = W_pos[128 + t], wp2 = W_pos[256 + t];
  float wn0 = W_noisy[t], wn1 = W_noisy[128 + t], wn2 = W_noisy[256 + t];
#pragma unroll
  for (int a = 0; a < 3; a++) {
    int i = tok + 256 * a;
    float p0 = ref_pos[i * 3], p1 = ref_pos[i * 3 + 1], p2 = ref_pos[i * 3 + 2];
    float r0 = r[i * 3], r1 = r[i * 3 + 1], r2 = r[i * 3 + 2];
    float c0 = p0 * wp0 + p1 * wp1 + p2 * wp2;
    x[i * 128 + t] = c0 + r0 * wn0 + r1 * wn1 + r2 * wn2;
    float cc = c0 + ctv;
    c_out[i * 128 + t] = cc;
    __syncthreads();
    rc[t] = fmaxf(cc, 0.f);
    __syncthreads();
    int out_id = t >> 2, q = t & 3;
    const float* Wm = (out_id < 16) ? Wca : Wcb;
    int ch = out_id & 15;
    float acc = 0.f;
#pragma unroll
    for (int kk = 0; kk < 32; kk++) { int k = q * 32 + kk; acc += rc[k] * Wm[k * 16 + ch]; }
    acc += __shfl_xor(acc, 1);
    acc += __shfl_xor(acc, 2);
    if (q == 0) { if (out_id < 16) ca[i * 16 + ch] = acc; else cb[i * 16 + ch] = acc; }
  }
}

// ---------------------------------------------------------------------------
// k_zp: zp[65536,16] = LN(z)@W_pair   grid 4096, block 256
__global__ __launch_bounds__(256) void k_zp(
    const float* __restrict__ z, const float* __restrict__ g,
    const float* __restrict__ lb, const float* __restrict__ W_pair,
    float* __restrict__ zp) {
  __shared__ float wT[16][132];
  __shared__ float zs[16][132];
  __shared__ float sWg[16], Bc[16];
  int t = threadIdx.x;
#pragma unroll
  for (int m = 0; m < 8; m++) {
    int e = t + 256 * m;
    int row = e >> 4, ch = e & 15;
    wT[ch][row] = g[row] * W_pair[e];
  }
  __syncthreads();
  if (t < 32) {
    int ch = t & 15;
    float a = 0.f;
    if (t < 16) {
#pragma unroll 8
      for (int k = 0; k < 128; k++) a += wT[ch][k];
      sWg[ch] = a;
    } else {
#pragma unroll 8
      for (int k = 0; k < 128; k++) a += lb[k] * W_pair[k * 16 + ch];
      Bc[ch] = a;
    }
  }
  int row = t >> 4, kk = (t & 15) * 8;
  long base = ((long)blockIdx.x * 16 + row) * 128 + kk;
  float4 a4 = *(const float4*)&z[base];
  float4 b4 = *(const float4*)&z[base + 4];
  *(float4*)&zs[row][kk] = a4;
  *(float4*)&zs[row][kk + 4] = b4;
  float ps = a4.x + a4.y + a4.z + a4.w + b4.x + b4.y + b4.z + b4.w;
  float pq = a4.x * a4.x + a4.y * a4.y + a4.z * a4.z + a4.w * a4.w +
             b4.x * b4.x + b4.y * b4.y + b4.z * b4.z + b4.w * b4.w;
#pragma unroll
  for (int o = 1; o < 16; o <<= 1) { ps += __shfl_xor(ps, o); pq += __shfl_xor(pq, o); }
  float m = ps * (1.f / 128.f);
  float rstd = rsqrtf(pq * (1.f / 128.f) - m * m + 1e-5f);
  __syncthreads();
  int ch = t & 15;
  float dotv = 0.f;
#pragma unroll 8
  for (int k4 = 0; k4 < 32; k4++) {
    float4 zv = *(float4*)&zs[row][k4 * 4];
    float4 wv = *(float4*)&wT[ch][k4 * 4];
    dotv += zv.x * wv.x + zv.y * wv.y + zv.z * wv.z + zv.w * wv.w;
  }
  zp[((long)blockIdx.x * 16 + row) * 16 + ch] = rstd * (dotv - m * sWg[ch]) + Bc[ch];
}

// ---------------------------------------------------------------------------
// k_pairM: pair + MFMA MLP + fused window bias.  grid 2304, block 256
__global__ __launch_bounds__(256) void k_pairM(
    const float* __restrict__ ref_pos, const int* __restrict__ uid,
    const float* __restrict__ Wpo, const float* __restrict__ Wisd,
    const float* __restrict__ Wmask, const float* __restrict__ W1,
    const float* __restrict__ W2, const float* __restrict__ W3,
    const float* __restrict__ zp, const float* __restrict__ ca,
    const float* __restrict__ cb, const float* __restrict__ lnp_g,
    const float* __restrict__ lnp_b, const float* __restrict__ Wb,
    float* __restrict__ pair_out, float* __restrict__ biasA) {
  int i = blockIdx.x / 3, jb = blockIdx.x % 3, t = threadIdx.x;
  __shared__ float jsx[256], jsy[256], jsz[256];
  __shared__ int jsu[256];
  __shared__ __align__(128) short stg[4][1280];
  __shared__ __align__(16) float pfs[4][1056];
  __shared__ float wgb[192];
  __shared__ float kbs[12];
  int jg = jb * 256 + t;
  jsx[t] = ref_pos[jg * 3];
  jsy[t] = ref_pos[jg * 3 + 1];
  jsz[t] = ref_pos[jg * 3 + 2];
  jsu[t] = uid[jg];
  if (t >= 64) {
    int e = t - 64;
    if (e < 192) {
      int bq = e >> 6, k = (e >> 2) & 15, h = e & 3;
      wgb[e] = lnp_g[bq * 16 + k] * Wb[bq * 64 + k * 4 + h];
    }
  }
  if (t >= 48 && t < 60) {
    int e = t - 48, bq = e >> 2, h = e & 3;
    float a = 0.f;
#pragma unroll
    for (int cc = 0; cc < 16; cc++) a += lnp_b[bq * 16 + cc] * Wb[bq * 64 + cc * 4 + h];
    kbs[e] = a;
  }
  int w = t >> 6, l = t & 63;
  int c = l & 15, gr = l >> 4;
  float pix = ref_pos[i * 3], piy = ref_pos[i * 3 + 1], piz = ref_pos[i * 3 + 2];
  int ui = uid[i];
  float w0c = Wpo[c], w1c = Wpo[16 + c], w2c = Wpo[32 + c];
  float wic = Wisd[c], wmc = Wmask[c], cac = ca[i * 16 + c];
  s16x8 bw0 = {bf1(W1[(4 * gr + 0) * 16 + c]), bf1(W1[(4 * gr + 1) * 16 + c]),
               bf1(W1[(4 * gr + 2) * 16 + c]), bf1(W1[(4 * gr + 3) * 16 + c]),
               (short)0, (short)0, (short)0, (short)0};
  s16x8 bw1 = {bf1(W2[(4 * gr + 0) * 16 + c]), bf1(W2[(4 * gr + 1) * 16 + c]),
               bf1(W2[(4 * gr + 2) * 16 + c]), bf1(W2[(4 * gr + 3) * 16 + c]),
               (short)0, (short)0, (short)0, (short)0};
  s16x8 bw2 = {bf1(W3[(4 * gr + 0) * 16 + c]), bf1(W3[(4 * gr + 1) * 16 + c]),
               bf1(W3[(4 * gr + 2) * 16 + c]), bf1(W3[(4 * gr + 3) * 16 + c]),
               (short)0, (short)0, (short)0, (short)0};
  __syncthreads();
  char* sb = (char*)&stg[w][0];
  unsigned sbase = (unsigned)(uintptr_t)sb;
  f32x4 z4 = {0.f, 0.f, 0.f, 0.f};
#pragma unroll
  for (int g = 0; g < 4; g++) {
    float p0_, p1_, p2_, p3_;
    {
      int jl0 = w * 64 + g * 16 + 4 * gr;
#pragma unroll
      for (int r = 0; r < 4; r++) {
        int jloc = jl0 + r;
        int j = jb * 256 + jloc;
        float d0 = pix - jsx[jloc], d1 = piy - jsy[jloc], d2 = piz - jsz[jloc];
        float mk = (ui == jsu[jloc]) ? 1.f : 0.f;
        float inv = 1.f / (1.f + d0 * d0 + d1 * d1 + d2 * d2);
        float zv = zp[((long)((i & 255) << 8) + jloc) * 16 + c];
        float cbv = cb[j * 16 + c];
        float pv = mk * (d0 * w0c + d1 * w1c + d2 * w2c + inv * wic + wmc) + zv + cbv + cac;
        if (r == 0) p0_ = pv; else if (r == 1) p1_ = pv; else if (r == 2) p2_ = pv; else p3_ = pv;
      }
    }
    char* wp = sb + g * 640 + c * 32 + gr * 8;
    unsigned ra = sbase + (unsigned)(g * 640 + c * 8 + gr * 128);
    *(uint2*)wp = make_uint2(bfpack(fmaxf(p0_, 0.f), fmaxf(p1_, 0.f)),
                             bfpack(fmaxf(p2_, 0.f), fmaxf(p3_, 0.f)));
    s16x4 tr0;
    asm volatile("s_waitcnt lgkmcnt(0)\n\tds_read_b64_tr_b16 %0, %1\n\ts_waitcnt lgkmcnt(0)"
                 : "=v"(tr0) : "v"(ra) : "memory");
    s16x8 a8 = {tr0[0], tr0[1], tr0[2], tr0[3], (short)0, (short)0, (short)0, (short)0};
    f32x4 h1 = __builtin_amdgcn_mfma_f32_16x16x32_bf16(a8, bw0, z4, 0, 0, 0);
    *(uint2*)wp = make_uint2(bfpack(fmaxf(h1[0], 0.f), fmaxf(h1[1], 0.f)),
                             bfpack(fmaxf(h1[2], 0.f), fmaxf(h1[3], 0.f)));
    s16x4 tr1;
    asm volatile("s_waitcnt lgkmcnt(0)\n\tds_read_b64_tr_b16 %0, %1\n\ts_waitcnt lgkmcnt(0)"
                 : "=v"(tr1) : "v"(ra) : "memory");
    s16x8 a8b = {tr1[0], tr1[1], tr1[2], tr1[3], (short)0, (short)0, (short)0, (short)0};
    f32x4 h2 = __builtin_amdgcn_mfma_f32_16x16x32_bf16(a8b, bw1, z4, 0, 0, 0);
    *(uint2*)wp = make_uint2(bfpack(fmaxf(h2[0], 0.f), fmaxf(h2[1], 0.f)),
                             bfpack(fmaxf(h2[2], 0.f), fmaxf(h2[3], 0.f)));
    s16x4 tr2;
    asm volatile("s_waitcnt lgkmcnt(0)\n\tds_read_b64_tr_b16 %0, %1\n\ts_waitcnt lgkmcnt(0)"
                 : "=v"(tr2) : "v"(ra) : "memory");
    s16x8 a8c = {tr2[0], tr2[1], tr2[2], tr2[3], (short)0, (short)0, (short)0, (short)0};
    f32x4 h3 = __builtin_amdgcn_mfma_f32_16x16x32_bf16(a8c, bw2, z4, 0, 0, 0);
    float f0 = p0_ + h3[0], f1 = p1_ + h3[1], f2 = p2_ + h3[2], f3 = p3_ + h3[3];
    {
      int jl0 = w * 64 + g * 16 + 4 * gr;
      long pb = ((long)i * 768 + (long)(jb * 256 + jl0)) * 16 + c;
      pair_out[pb] = f0;
      pair_out[pb + 16] = f1;
      pair_out[pb + 32] = f2;
      pair_out[pb + 48] = f3;
    }
    *(float4*)&pfs[w][g * 264 + c * 16 + 4 * gr] = make_float4(f0, f1, f2, f3);
  }
  asm volatile("s_waitcnt lgkmcnt(0)" ::: "memory");
  int qb = i >> 5;
  int j = jb * 256 + t;
  unsigned jw = (unsigned)(j - (qb * 32 - 48));
  if (jw < 128u) {
    int gt = (t >> 4) & 3, jr = t & 15;
    float v[16];
#pragma unroll
    for (int cc = 0; cc < 16; cc++) v[cc] = pfs[w][gt * 264 + cc * 16 + jr];
    float m = 0.f;
#pragma unroll
    for (int cc = 0; cc < 16; cc++) m += v[cc];
    m *= (1.f / 16.f);
    float vv = 0.f;
#pragma unroll
    for (int cc = 0; cc < 16; cc++) { float d = v[cc] - m; vv += d * d; }
    float rs = rsqrtf(vv * (1.f / 16.f) + 1e-5f);
    float nrm[16];
#pragma unroll
    for (int cc = 0; cc < 16; cc++) nrm[cc] = (v[cc] - m) * rs;
    int qi = i & 31;
#pragma unroll
    for (int bq = 0; bq < 3; bq++) {
      float o0 = kbs[bq * 4 + 0], o1 = kbs[bq * 4 + 1];
      float o2 = kbs[bq * 4 + 2], o3 = kbs[bq * 4 + 3];
#pragma unroll
      for (int k = 0; k < 16; k++) {
        float nv = nrm[k];
        float4 wv = *(float4*)&wgb[bq * 64 + k * 4];
        o0 += nv * wv.x; o1 += nv * wv.y; o2 += nv * wv.z; o3 += nv * wv.w;
      }
      long base = (long)(bq * 96 + qb * 4) * 4096 + (long)qi * 128 + jw;
      biasA[base] = o0;
      biasA[base + 4096] = o1;
      biasA[base + 2 * 4096] = o2;
      biasA[base + 3 * 4096] = o3;
    }
  }
}

// ---------------------------------------------------------------------------
// k_qkvg (layer 0 only): grid 384 (rb*8+bn), block 256
__global__ __launch_bounds__(256) void k_qkvg(
    const float* __restrict__ x, const float* __restrict__ lng,
    const float* __restrict__ lnb, const float* __restrict__ Wq,
    const float* __restrict__ Wk, const float* __restrict__ Wv,
    const float* __restrict__ Wg, float* __restrict__ qkvg) {
  __shared__ float As[128][18];
  __shared__ float Ws[128][66];
  int t = threadIdx.x;
  int rb = blockIdx.x >> 3, bn = blockIdx.x & 7;
  int r0 = rb * 16;
  const float* Wm = (bn < 2) ? Wq : (bn < 4) ? Wk : (bn < 6) ? Wv : Wg;
  int c0 = (bn & 1) * 64;
  int ncol0 = (bn >> 1) * 128 + c0;
#pragma unroll
  for (int m = 0; m < 8; m++) {
    int idx = t + 256 * m;
    int row = idx >> 4, c4 = (idx & 15) * 4;
    *(float4*)&Ws[row][c4] = *(const float4*)&Wm[row * 128 + c0 + c4];
  }
  {
    int rr = t >> 4, tt = t & 15;
    int row = r0 + rr;
    float4 x0 = *(const float4*)&x[row * 128 + tt * 8];
    float4 x1 = *(const float4*)&x[row * 128 + tt * 8 + 4];
    float ps = x0.x + x0.y + x0.z + x0.w + x1.x + x1.y + x1.z + x1.w;
    float pq = x0.x * x0.x + x0.y * x0.y + x0.z * x0.z + x0.w * x0.w +
               x1.x * x1.x + x1.y * x1.y + x1.z * x1.z + x1.w * x1.w;
#pragma unroll
    for (int o = 1; o < 16; o <<= 1) { ps += __shfl_xor(ps, o); pq += __shfl_xor(pq, o); }
    float m = ps * (1.f / 128.f);
    float rstd = rsqrtf(pq * (1.f / 128.f) - m * m + 1e-5f);
    float4 g0 = *(const float4*)&lng[tt * 8], g1 = *(const float4*)&lng[tt * 8 + 4];
    float4 b0 = *(const float4*)&lnb[tt * 8], b1 = *(const float4*)&lnb[tt * 8 + 4];
    As[tt * 8 + 0][rr] = (x0.x - m) * rstd * g0.x + b0.x;
    As[tt * 8 + 1][rr] = (x0.y - m) * rstd * g0.y + b0.y;
    As[tt * 8 + 2][rr] = (x0.z - m) * rstd * g0.z + b0.z;
    As[tt * 8 + 3][rr] = (x0.w - m) * rstd * g0.w + b0.w;
    As[tt * 8 + 4][rr] = (x1.x - m) * rstd * g1.x + b1.x;
    As[tt * 8 + 5][rr] = (x1.y - m) * rstd * g1.y + b1.y;
    As[tt * 8 + 6][rr] = (x1.z - m) * rstd * g1.z + b1.z;
    As[tt * 8 + 7][rr] = (x1.w - m) * rstd * g1.w + b1.w;
  }
  __syncthreads();
  int ty = t >> 5, tx = t & 31;
  float a00 = 0, a01 = 0, a10 = 0, a11 = 0;
#pragma unroll 8
  for (int k = 0; k < 128; k++) {
    float2 a2 = *(float2*)&As[k][ty * 2];
    float2 w2 = *(float2*)&Ws[k][tx * 2];
    a00 += a2.x * w2.x; a01 += a2.x * w2.y;
    a10 += a2.y * w2.x; a11 += a2.y * w2.y;
  }
  int row = r0 + ty * 2;
  float2 o0 = {a00, a01}, o1 = {a10, a11};
  *(float2*)&qkvg[row * 512 + ncol0 + tx * 2] = o0;
  *(float2*)&qkvg[(row + 1) * 512 + ncol0 + tx * 2] = o1;
}

// ---------------------------------------------------------------------------
// k_attn2: windowed attention, 16-row q-tiles.  grid 192 (qt*4+h), block 256
__global__ __launch_bounds__(256) void k_attn2(
    const float* __restrict__ qkvg, const float* __restrict__ biasb,
    float* __restrict__ og) {
  int qt = blockIdx.x >> 2, h = blockIdx.x & 3, t = threadIdx.x;
  int i0 = qt * 16;
  int qb32 = qt >> 1;
  int lo = qb32 * 32 - 48;
  int qoff = (qt & 1) * 16;
  __shared__ float qs[16][36];
  __shared__ float ks[128][36];
  __shared__ float vs[128][36];
  __shared__ float L[16][132];
  {
    int e = t * 8;
    int qi = e >> 7, k8 = e & 127;
    const float* bb = &biasb[(long)(qb32 * 4 + h) * 4096 + (long)(qoff + qi) * 128];
#pragma unroll
    for (int m = 0; m < 2; m++) {
      int k4 = k8 + m * 4;
      int j4 = lo + k4;
      float4 bv;
      if (j4 >= 0 && j4 <= 764) bv = *(const float4*)&bb[k4];
      else bv = make_float4(-1e30f, -1e30f, -1e30f, -1e30f);
      *(float4*)&L[qi][k4] = bv;
    }
  }
  if (t < 128) {
    int qi = t >> 3, dq = (t & 7) * 4;
    *(float4*)&qs[qi][dq] = *(const float4*)&qkvg[(i0 + qi) * 512 + h * 32 + dq];
  }
  {
    int kj = t >> 1, dh = (t & 1) * 16;
    int j = lo + kj;
    if (j >= 0 && j < 768) {
      const float4* sk = (const float4*)&qkvg[j * 512 + 128 + h * 32 + dh];
      const float4* sv = (const float4*)&qkvg[j * 512 + 256 + h * 32 + dh];
#pragma unroll
      for (int m = 0; m < 4; m++) {
        *(float4*)&ks[kj][dh + 4 * m] = sk[m];
        *(float4*)&vs[kj][dh + 4 * m] = sv[m];
      }
    } else {
      float4 zz = {0, 0, 0, 0};
#pragma unroll
      for (int m = 0; m < 4; m++) {
        *(float4*)&ks[kj][dh + 4 * m] = zz;
        *(float4*)&vs[kj][dh + 4 * m] = zz;
      }
    }
  }
  __syncthreads();
  const float scale = 0.17677669529663687f;
  {
    int qi = t & 15, kb = t >> 4;
    float4 qr[8];
#pragma unroll
    for (int m = 0; m < 8; m++) qr[m] = *(float4*)&qs[qi][m * 4];
#pragma unroll
    for (int kk = 0; kk < 8; kk++) {
      int kj = kb * 8 + kk;
      float acc = 0.f;
#pragma unroll
      for (int m = 0; m < 8; m++) {
        float4 kv = *(float4*)&ks[kj][m * 4];
        acc += qr[m].x * kv.x + qr[m].y * kv.y + qr[m].z * kv.z + qr[m].w * kv.w;
      }
      L[qi][kj] += acc * scale;
    }
  }
  __syncthreads();
  int qi = t >> 4, sg = t & 15;
  float mx = -1e30f;
#pragma unroll
  for (int k2 = 0; k2 < 8; k2++) mx = fmaxf(mx, L[qi][sg * 8 + k2]);
#pragma unroll
  for (int o = 1; o < 16; o <<= 1) mx = fmaxf(mx, __shfl_xor(mx, o));
  float sum = 0.f;
#pragma unroll
  for (int k2 = 0; k2 < 8; k2++) {
    int kj = sg * 8 + k2;
    float e = __expf(L[qi][kj] - mx);
    L[qi][kj] = e;
    sum += e;
  }
#pragma unroll
  for (int o = 1; o < 16; o <<= 1) sum += __shfl_xor(sum, o);
  float rden = 1.f / sum;
  __syncthreads();
  {
    int d2 = (t & 15) * 2;
    float a0 = 0.f, a1 = 0.f;
#pragma unroll 8
    for (int kj = 0; kj < 128; kj++) {
      float p = L[qi][kj];
      float2 v = *(float2*)&vs[kj][d2];
      a0 += p * v.x; a1 += p * v.y;
    }
    int i = i0 + qi;
    float2 gr = *(const float2*)&qkvg[i * 512 + 384 + h * 32 + d2];
    float2 o2;
    o2.x = a0 * rden * sigmoidf_(gr.x);
    o2.y = a1 * rden * sigmoidf_(gr.y);
    *(float2*)&og[i * 128 + h * 32 + d2] = o2;
  }
}

// ---------------------------------------------------------------------------
// k_fusedT<MODE>: x += og@Wo; a=LN(x); x += relu(a@Wt1)@Wt2; then
//  MODE 1: qkvg_next = LN_next(x) @ [Wq|Wk|Wv|Wg]
//  MODE 2: qout = relu(x@W_proj), a_out = mean (k_final fused)
// grid 256 (3 rows/block, 1/CU), block 384.  (all GEMM loops: unroll 8)
template <int MODE>
__global__ __launch_bounds__(384) void k_fusedT(
    const float* __restrict__ og, const float* __restrict__ Wo,
    const float* __restrict__ g2, const float* __restrict__ b2,
    const float* __restrict__ Wt1, const float* __restrict__ Wt2,
    float* __restrict__ x,
    const float* __restrict__ lng_n, const float* __restrict__ lnb_n,
    const float* __restrict__ Wq, const float* __restrict__ Wk,
    const float* __restrict__ Wv, const float* __restrict__ Wg,
    float* __restrict__ qkvg, const float* __restrict__ W_proj,
    float* __restrict__ out) {
  int t = threadIdx.x;
  int r0 = blockIdx.x * 3;
  __shared__ float osr[3][128];
  __shared__ float xns[3][128];
  __shared__ float asr[3][128];
  __shared__ float hs[3][512];
  __shared__ float part[4][3][128];
  __shared__ float red[12];
  {
    int rr = t >> 7, c = t & 127;
    osr[rr][c] = og[(r0 + rr) * 128 + c];
    xns[rr][c] = x[(r0 + rr) * 128 + c];
  }
  __syncthreads();
  // ---- GEMM1 (k-split 4) ----
  {
    int c4 = (t & 31) * 4, row = (t >> 5) % 3, q = t / 96;
    int k0 = q * 32;
    float a0 = 0.f, a1 = 0.f, a2 = 0.f, a3 = 0.f;
#pragma unroll 8
    for (int kk = 0; kk < 32; kk++) {
      int k = k0 + kk;
      float4 w = *(const float4*)&Wo[k * 128 + c4];
      float av = osr[row][k];
      a0 += av * w.x; a1 += av * w.y; a2 += av * w.z; a3 += av * w.w;
    }
    *(float4*)&part[q][row][c4] = make_float4(a0, a1, a2, a3);
  }
  __syncthreads();
  // ---- combine + LN ----
  {
    int rr = t >> 7, c = t & 127;
    float xv = xns[rr][c] + part[0][rr][c] + part[1][rr][c] + part[2][rr][c] + part[3][rr][c];
    float ps = xv, pq = xv * xv;
#pragma unroll
    for (int o = 1; o < 64; o <<= 1) { ps += __shfl_xor(ps, o); pq += __shfl_xor(pq, o); }
    int wv = t >> 6;
    if ((t & 63) == 0) { red[wv] = ps; red[6 + wv] = pq; }
    __syncthreads();
    float mean = (red[2 * rr] + red[2 * rr + 1]) * (1.f / 128.f);
    float var = (red[6 + 2 * rr] + red[6 + 2 * rr + 1]) * (1.f / 128.f) - mean * mean;
    float rstd = rsqrtf(var + 1e-5f);
    xns[rr][c] = xv;
    asr[rr][c] = (xv - mean) * rstd * g2[c] + b2[c];
  }
  __syncthreads();
  // ---- GEMM2: hs = relu(asr @ Wt1) ----
  {
    int c4 = (t & 127) * 4, row = t >> 7;
    float a0 = 0.f, a1 = 0.f, a2 = 0.f, a3 = 0.f;
#pragma unroll 8
    for (int k = 0; k < 128; k++) {
      float4 w = *(const float4*)&Wt1[k * 512 + c4];
      float av = asr[row][k];
      a0 += av * w.x; a1 += av * w.y; a2 += av * w.z; a3 += av * w.w;
    }
    *(float4*)&hs[row][c4] = make_float4(fmaxf(a0, 0.f), fmaxf(a1, 0.f),
                                         fmaxf(a2, 0.f), fmaxf(a3, 0.f));
  }
  __syncthreads();
  // ---- GEMM3 (k-split 4) ----
  {
    int c4 = (t & 31) * 4, row = (t >> 5) % 3, q = t / 96;
    int k0 = q * 128;
    float a0 = 0.f, a1 = 0.f, a2 = 0.f, a3 = 0.f;
#pragma unroll 8
    for (int kk = 0; kk < 128; kk++) {
      int k = k0 + kk;
      float4 w = *(const float4*)&Wt2[k * 128 + c4];
      float hv = hs[row][k];
      a0 += hv * w.x; a1 += hv * w.y; a2 += hv * w.z; a3 += hv * w.w;
    }
    *(float4*)&part[q][row][c4] = make_float4(a0, a1, a2, a3);
  }
  __syncthreads();
  // ---- final x + optional fused tails ----
  {
    int rr = t >> 7, c = t & 127;
    float xf = xns[rr][c] + part[0][rr][c] + part[1][rr][c] +
               part[2][rr][c] + part[3][rr][c];
    x[(r0 + rr) * 128 + c] = xf;
    xns[rr][c] = xf;
  }
  if (MODE == 1) {
    __syncthreads();
    {
      int rr = t >> 7, c = t & 127;
      float xv = xns[rr][c];
      float ps = xv, pq = xv * xv;
#pragma unroll
      for (int o = 1; o < 64; o <<= 1) { ps += __shfl_xor(ps, o); pq += __shfl_xor(pq, o); }
      int wv = t >> 6;
      if ((t & 63) == 0) { red[wv] = ps; red[6 + wv] = pq; }
      __syncthreads();
      float mean = (red[2 * rr] + red[2 * rr + 1]) * (1.f / 128.f);
      float var = (red[6 + 2 * rr] + red[6 + 2 * rr + 1]) * (1.f / 128.f) - mean * mean;
      float rstd = rsqrtf(var + 1e-5f);
      asr[rr][c] = (xv - mean) * rstd * lng_n[c] + lnb_n[c];
    }
    __syncthreads();
    {
      int c4 = (t & 127) * 4, row = t >> 7;
      int mtx = c4 >> 7, lc = c4 & 127;
      const float* Wm = (mtx == 0) ? Wq : (mtx == 1) ? Wk : (mtx == 2) ? Wv : Wg;
      float a0 = 0.f, a1 = 0.f, a2 = 0.f, a3 = 0.f;
#pragma unroll 8
      for (int k = 0; k < 128; k++) {
        float4 w = *(const float4*)&Wm[k * 128 + lc];
        float av = asr[row][k];
        a0 += av * w.x; a1 += av * w.y; a2 += av * w.z; a3 += av * w.w;
      }
      *(float4*)&qkvg[(r0 + row) * 512 + c4] = make_float4(a0, a1, a2, a3);
    }
  }
  if (MODE == 2) {
    __syncthreads();
    int tk = blockIdx.x;
    float a0 = 0.f, a1 = 0.f, a2 = 0.f;
#pragma unroll 8
    for (int k = 0; k < 128; k++) {
      float w = W_proj[k * 384 + t];
      a0 += xns[0][k] * w; a1 += xns[1][k] * w; a2 += xns[2][k] * w;
    }
    a0 = fmaxf(a0, 0.f); a1 = fmaxf(a1, 0.f); a2 = fmaxf(a2, 0.f);
    out[98304 + (tk * 3 + 0) * 384 + t] = a0;
    out[98304 + (tk * 3 + 1) * 384 + t] = a1;
    out[98304 + (tk * 3 + 2) * 384 + t] = a2;
    out[tk * 384 + t] = (a0 + a1 + a2) * (1.f / 3.f);
  }
}

// ---------------------------------------------------------------------------
extern "C" void kernel_launch(void* const* d_in, const int* in_sizes, int n_in,
                              void* d_out, int out_size, void* d_ws, size_t ws_size,
                              hipStream_t stream) {
  const float* ref_pos  = (const float*)d_in[0];
  const int*   uid      = (const int*)d_in[1];
  const float* r        = (const float*)d_in[2];
  const float* s        = (const float*)d_in[3];
  const float* z        = (const float*)d_in[4];
  const float* W_pos    = (const float*)d_in[5];
  const float* Wpo      = (const float*)d_in[6];
  const float* Wisd     = (const float*)d_in[7];
  const float* Wmask    = (const float*)d_in[8];
  const float* Wca      = (const float*)d_in[9];
  const float* Wcb      = (const float*)d_in[10];
  const float* ln_s_g   = (const float*)d_in[11];
  const float* ln_s_b   = (const float*)d_in[12];
  const float* W_single = (const float*)d_in[13];
  const float* ln_z_g   = (const float*)d_in[14];
  const float* ln_z_b   = (const float*)d_in[15];
  const float* W_pair   = (const float*)d_in[16];
  const float* W_noisy  = (const float*)d_in[17];
  const float* W_mlp1   = (const float*)d_in[18];
  const float* W_mlp2   = (const float*)d_in[19];
  const float* W_mlp3   = (const float*)d_in[20];
  const float* at_ln_g  = (const float*)d_in[21];
  const float* at_ln_b  = (const float*)d_in[22];
  const float* at_Wq    = (const float*)d_in[23];
  const float* at_Wk    = (const float*)d_in[24];
  const float* at_Wv    = (const float*)d_in[25];
  const float* at_Wg    = (const float*)d_in[26];
  const float* at_lnp_g = (const float*)d_in[27];
  const float* at_lnp_b = (const float*)d_in[28];
  const float* at_Wb    = (const float*)d_in[29];
  const float* at_Wo    = (const float*)d_in[30];
  const float* at_ln2_g = (const float*)d_in[31];
  const float* at_ln2_b = (const float*)d_in[32];
  const float* at_Wt1   = (const float*)d_in[33];
  const float* at_Wt2   = (const float*)d_in[34];
  const float* W_proj   = (const float*)d_in[35];
  float* out = (float*)d_out;
  float* W = (float*)d_ws;
  float* x     = W;                 //   98304
  float* ca    = W + 98304;         //   12288
  float* cb    = W + 110592;        //   12288
  float* zp    = W + 122880;        // 1048576
  float* biasA = W + 1171456;       // 1179648
  float* qkvg  = W + 2351104;       //  393216
  float* og    = W + 2744320;       //   98304

  k_zp<<<4096, 256, 0, stream>>>(z, ln_z_g, ln_z_b, W_pair, zp);
  k_tokatoms<<<256, 128, 0, stream>>>(s, ln_s_g, ln_s_b, W_single, ref_pos, r,
                                      W_pos, W_noisy, Wca, Wcb,
                                      out + 393216, x, ca, cb);
  k_pairM<<<2304, 256, 0, stream>>>(ref_pos, uid, Wpo, Wisd, Wmask, W_mlp1, W_mlp2,
                                    W_mlp3, zp, ca, cb, at_lnp_g, at_lnp_b, at_Wb,
                                    out + 491520, biasA);
  k_qkvg<<<384, 256, 0, stream>>>(x, at_ln_g, at_ln_b, at_Wq, at_Wk, at_Wv, at_Wg, qkvg);
  // layer 0
  k_attn2<<<192, 256, 0, stream>>>(qkvg, biasA, og);
  k_fusedT<1><<<256, 384, 0, stream>>>(og, at_Wo, at_ln2_g, at_ln2_b, at_Wt1, at_Wt2, x,
                                       at_ln_g + 128, at_ln_b + 128,
                                       at_Wq + 16384, at_Wk + 16384,
                                       at_Wv + 16384, at_Wg + 16384, qkvg,
                                       nullptr, nullptr);
  // layer 1
  k_attn2<<<192, 256, 0, stream>>>(qkvg, biasA + 393216, og);
  k_fusedT<1><<<256, 384, 0, stream>>>(og, at_Wo + 16384, at_ln2_g + 128, at_ln2_b + 128,
                                       at_Wt1 + 65536, at_Wt2 + 65536, x,
                                       at_ln_g + 256, at_ln_b + 256,
                                       at_Wq + 32768, at_Wk + 32768,
                                       at_Wv + 32768, at_Wg + 32768, qkvg,
                                       nullptr, nullptr);
  // layer 2
  k_attn2<<<192, 256, 0, stream>>>(qkvg, biasA + 786432, og);
  k_fusedT<2><<<256, 384, 0, stream>>>(og, at_Wo + 32768, at_ln2_g + 256, at_ln2_b + 256,
                                       at_Wt1 + 131072, at_Wt2 + 131072, x,
                                       nullptr, nullptr, nullptr, nullptr,
                                       nullptr, nullptr, nullptr, W_proj, out);
}

// Round 15
// 155.876 us; speedup vs baseline: 1.3349x; 1.0163x over previous
//
#include <hip/hip_runtime.h>
#include <math.h>

// N=768 atoms, T=256 tokens, CA=128, CP=16, CZ=128, CS=384, CT=384, H=4, DH=32
// d_out: a_out[256*384]@0, qout[768*384]@98304, c[768*128]@393216, pair[768*768*16]@491520

__device__ __forceinline__ float sigmoidf_(float v) { return 1.f / (1.f + __expf(-v)); }

typedef __attribute__((ext_vector_type(4))) short s16x4;
typedef __attribute__((ext_vector_type(8))) short s16x8;
typedef __attribute__((ext_vector_type(4))) float f32x4;

__device__ __forceinline__ unsigned bfpack(float a, float b) {
  return (__float_as_uint(a) >> 16) | (__float_as_uint(b) & 0xFFFF0000u);
}
__device__ __forceinline__ short bf1(float a) { return (short)(__float_as_uint(a) >> 16); }

// ---------------------------------------------------------------------------
// k_front: bid<4096 -> zp ; bid>=4096 -> tokatoms (token = bid-4096)
// grid 4352, block 256.  Shared pool 4624 floats (18.5 KB).
__global__ __launch_bounds__(256) void k_front(
    const float* __restrict__ z, const float* __restrict__ zg,
    const float* __restrict__ zlb, const float* __restrict__ W_pair,
    float* __restrict__ zp,
    const float* __restrict__ s, const float* __restrict__ g,
    const float* __restrict__ b, const float* __restrict__ W_single,
    const float* __restrict__ ref_pos, const float* __restrict__ r,
    const float* __restrict__ W_pos, const float* __restrict__ W_noisy,
    const float* __restrict__ Wca, const float* __restrict__ Wcb,
    float* __restrict__ c_out, float* __restrict__ x,
    float* __restrict__ ca, float* __restrict__ cb) {
  __shared__ __align__(16) float sm[4624];
  int t = threadIdx.x;
  int bid = blockIdx.x;
  if (bid < 4096) {
    // ---------------- zp: zp[bid*16+row][ch] = LN(z)@W_pair ----------------
    float* wT = sm;             // [16][132] ch-major
    float* zs = sm + 2112;      // [16][132]
    float* sWg = sm + 4224;     // [16]
    float* Bc = sm + 4240;      // [16]
#pragma unroll
    for (int m = 0; m < 8; m++) {
      int e = t + 256 * m;
      int row = e >> 4, ch = e & 15;
      wT[ch * 132 + row] = zg[row] * W_pair[e];
    }
    __syncthreads();
    if (t < 32) {
      int ch = t & 15;
      float a = 0.f;
      if (t < 16) {
#pragma unroll 8
        for (int k = 0; k < 128; k++) a += wT[ch * 132 + k];
        sWg[ch] = a;
      } else {
#pragma unroll 8
        for (int k = 0; k < 128; k++) a += zlb[k] * W_pair[k * 16 + ch];
        Bc[ch] = a;
      }
    }
    int row = t >> 4, kk = (t & 15) * 8;
    long base = ((long)bid * 16 + row) * 128 + kk;
    float4 a4 = *(const float4*)&z[base];
    float4 b4 = *(const float4*)&z[base + 4];
    *(float4*)&zs[row * 132 + kk] = a4;
    *(float4*)&zs[row * 132 + kk + 4] = b4;
    float ps = a4.x + a4.y + a4.z + a4.w + b4.x + b4.y + b4.z + b4.w;
    float pq = a4.x * a4.x + a4.y * a4.y + a4.z * a4.z + a4.w * a4.w +
               b4.x * b4.x + b4.y * b4.y + b4.z * b4.z + b4.w * b4.w;
#pragma unroll
    for (int o = 1; o < 16; o <<= 1) { ps += __shfl_xor(ps, o); pq += __shfl_xor(pq, o); }
    float m = ps * (1.f / 128.f);
    float rstd = rsqrtf(pq * (1.f / 128.f) - m * m + 1e-5f);
    __syncthreads();
    int ch = t & 15;
    float dotv = 0.f;
#pragma unroll 8
    for (int k4 = 0; k4 < 32; k4++) {
      float4 zv = *(float4*)&zs[row * 132 + k4 * 4];
      float4 wv = *(float4*)&wT[ch * 132 + k4 * 4];
      dotv += zv.x * wv.x + zv.y * wv.y + zv.z * wv.z + zv.w * wv.w;
    }
    zp[((long)bid * 16 + row) * 16 + ch] = rstd * (dotv - m * sWg[ch]) + Bc[ch];
  } else {
    // ---------------- tokatoms (guards t<128; barriers uniform) ------------
    int tok = bid - 4096;
    float* sln = sm;            // [384]
    float* ws = sm + 384;       // [32*128]
    float* red = sm + 4480;     // [4]
    float* rc = sm + 4488;      // [128]
    float v0 = 0.f, v1 = 0.f, v2 = 0.f;
    if (t < 128) {
      v0 = s[tok * 384 + t]; v1 = s[tok * 384 + 128 + t]; v2 = s[tok * 384 + 256 + t];
      float ps = v0 + v1 + v2, pq = v0 * v0 + v1 * v1 + v2 * v2;
#pragma unroll
      for (int o = 1; o < 64; o <<= 1) { ps += __shfl_xor(ps, o); pq += __shfl_xor(pq, o); }
      if ((t & 63) == 0) { red[t >> 6] = ps; red[2 + (t >> 6)] = pq; }
    }
    __syncthreads();
    float ctv = 0.f;
    if (t < 128) {
      float mean = (red[0] + red[1]) * (1.f / 384.f);
      float var = (red[2] + red[3]) * (1.f / 384.f) - mean * mean;
      float rstd = rsqrtf(var + 1e-5f);
      sln[t] = (v0 - mean) * rstd * g[t] + b[t];
      sln[128 + t] = (v1 - mean) * rstd * g[128 + t] + b[128 + t];
      sln[256 + t] = (v2 - mean) * rstd * g[256 + t] + b[256 + t];
    }
    for (int c0 = 0; c0 < 384; c0 += 32) {
      __syncthreads();
#pragma unroll
      for (int m = 0; m < 4; m++) {
        int idx = (t + 256 * m) * 4;
        *(float4*)&ws[idx] = *(const float4*)&W_single[c0 * 128 + idx];
      }
      __syncthreads();
      if (t < 128) {
#pragma unroll 8
        for (int kk = 0; kk < 32; kk++) ctv += sln[c0 + kk] * ws[kk * 128 + t];
      }
    }
    float wp0 = 0.f, wp1 = 0.f, wp2 = 0.f, wn0 = 0.f, wn1 = 0.f, wn2 = 0.f;
    if (t < 128) {
      wp0 = W_pos[t]; wp1 = W_pos[128 + t]; wp2 = W_pos[256 + t];
      wn0 = W_noisy[t]; wn1 = W_noisy[128 + t]; wn2 = W_noisy[256 + t];
    }
#pragma unroll
    for (int a = 0; a < 3; a++) {
      int i = tok + 256 * a;
      float cc = 0.f;
      if (t < 128) {
        float p0 = ref_pos[i * 3], p1 = ref_pos[i * 3 + 1], p2 = ref_pos[i * 3 + 2];
        float r0 = r[i * 3], r1 = r[i * 3 + 1], r2 = r[i * 3 + 2];
        float c0 = p0 * wp0 + p1 * wp1 + p2 * wp2;
        x[i * 128 + t] = c0 + r0 * wn0 + r1 * wn1 + r2 * wn2;
        cc = c0 + ctv;
        c_out[i * 128 + t] = cc;
      }
      __syncthreads();
      if (t < 128) rc[t] = fmaxf(cc, 0.f);
      __syncthreads();
      if (t < 128) {
        int out_id = t >> 2, q = t & 3;
        const float* Wm = (out_id < 16) ? Wca : Wcb;
        int ch = out_id & 15;
        float acc = 0.f;
#pragma unroll
        for (int kk = 0; kk < 32; kk++) { int k = q * 32 + kk; acc += rc[k] * Wm[k * 16 + ch]; }
        acc += __shfl_xor(acc, 1);
        acc += __shfl_xor(acc, 2);
        if (q == 0) { if (out_id < 16) ca[i * 16 + ch] = acc; else cb[i * 16 + ch] = acc; }
      }
    }
  }
}

// ---------------------------------------------------------------------------
// k_pairq: bid<2304 -> pairM ; bid>=2304 -> qkvg layer-0 (direct weights)
// grid 2688, block 256
__global__ __launch_bounds__(256) void k_pairq(
    const float* __restrict__ ref_pos, const int* __restrict__ uid,
    const float* __restrict__ Wpo, const float* __restrict__ Wisd,
    const float* __restrict__ Wmask, const float* __restrict__ W1,
    const float* __restrict__ W2, const float* __restrict__ W3,
    const float* __restrict__ zp, const float* __restrict__ ca,
    const float* __restrict__ cb, const float* __restrict__ lnp_g,
    const float* __restrict__ lnp_b, const float* __restrict__ Wb,
    float* __restrict__ pair_out, float* __restrict__ biasA,
    const float* __restrict__ x, const float* __restrict__ lng,
    const float* __restrict__ lnb, const float* __restrict__ Wq,
    const float* __restrict__ Wk, const float* __restrict__ Wv,
    const float* __restrict__ Wg, float* __restrict__ qkvg) {
  __shared__ float jsx[256], jsy[256], jsz[256];
  __shared__ int jsu[256];
  __shared__ __align__(128) short stg[4][1280];
  __shared__ __align__(16) float pfs[4][1056];
  __shared__ float wgb[192];
  __shared__ float kbs[12];
  int t = threadIdx.x;
  int bid = blockIdx.x;
  if (bid >= 2304) {
    // ---------------- qkvg layer 0: 2 rows per block --------------------
    int r0 = (bid - 2304) * 2;
    float* asr_ = jsx;   // [2][128]
    float* red_ = jsy;   // [8]
    int row = t >> 7, c = t & 127;
    float xv = x[(r0 + row) * 128 + c];
    {
      float ps = xv, pq = xv * xv;
#pragma unroll
      for (int o = 1; o < 64; o <<= 1) { ps += __shfl_xor(ps, o); pq += __shfl_xor(pq, o); }
      int wv = t >> 6;
      if ((t & 63) == 0) { red_[wv] = ps; red_[4 + wv] = pq; }
      __syncthreads();
      float mean = (red_[2 * row] + red_[2 * row + 1]) * (1.f / 128.f);
      float var = (red_[4 + 2 * row] + red_[4 + 2 * row + 1]) * (1.f / 128.f) - mean * mean;
      float rstd = rsqrtf(var + 1e-5f);
      asr_[row * 128 + c] = (xv - mean) * rstd * lng[c] + lnb[c];
    }
    __syncthreads();
    {
      int c4 = (t & 127) * 4, row2 = t >> 7;
      int mtx = c4 >> 7, lc = c4 & 127;
      const float* Wm = (mtx == 0) ? Wq : (mtx == 1) ? Wk : (mtx == 2) ? Wv : Wg;
      float a0 = 0.f, a1 = 0.f, a2 = 0.f, a3 = 0.f;
#pragma unroll 8
      for (int k = 0; k < 128; k++) {
        float4 w = *(const float4*)&Wm[k * 128 + lc];
        float av = asr_[row2 * 128 + k];
        a0 += av * w.x; a1 += av * w.y; a2 += av * w.z; a3 += av * w.w;
      }
      *(float4*)&qkvg[(r0 + row2) * 512 + c4] = make_float4(a0, a1, a2, a3);
    }
    return;
  }
  // ---------------- pairM (unchanged body) ------------------------------
  int i = bid / 3, jb = bid % 3;
  int jg = jb * 256 + t;
  jsx[t] = ref_pos[jg * 3];
  jsy[t] = ref_pos[jg * 3 + 1];
  jsz[t] = ref_pos[jg * 3 + 2];
  jsu[t] = uid[jg];
  if (t >= 64) {
    int e = t - 64;
    if (e < 192) {
      int bq = e >> 6, k = (e >> 2) & 15, h = e & 3;
      wgb[e] = lnp_g[bq * 16 + k] * Wb[bq * 64 + k * 4 + h];
    }
  }
  if (t >= 48 && t < 60) {
    int e = t - 48, bq = e >> 2, h = e & 3;
    float a = 0.f;
#pragma unroll
    for (int cc = 0; cc < 16; cc++) a += lnp_b[bq * 16 + cc] * Wb[bq * 64 + cc * 4 + h];
    kbs[e] = a;
  }
  int w = t >> 6, l = t & 63;
  int c = l & 15, gr = l >> 4;
  float pix = ref_pos[i * 3], piy = ref_pos[i * 3 + 1], piz = ref_pos[i * 3 + 2];
  int ui = uid[i];
  float w0c = Wpo[c], w1c = Wpo[16 + c], w2c = Wpo[32 + c];
  float wic = Wisd[c], wmc = Wmask[c], cac = ca[i * 16 + c];
  s16x8 bw0 = {bf1(W1[(4 * gr + 0) * 16 + c]), bf1(W1[(4 * gr + 1) * 16 + c]),
               bf1(W1[(4 * gr + 2) * 16 + c]), bf1(W1[(4 * gr + 3) * 16 + c]),
               (short)0, (short)0, (short)0, (short)0};
  s16x8 bw1 = {bf1(W2[(4 * gr + 0) * 16 + c]), bf1(W2[(4 * gr + 1) * 16 + c]),
               bf1(W2[(4 * gr + 2) * 16 + c]), bf1(W2[(4 * gr + 3) * 16 + c]),
               (short)0, (short)0, (short)0, (short)0};
  s16x8 bw2 = {bf1(W3[(4 * gr + 0) * 16 + c]), bf1(W3[(4 * gr + 1) * 16 + c]),
               bf1(W3[(4 * gr + 2) * 16 + c]), bf1(W3[(4 * gr + 3) * 16 + c]),
               (short)0, (short)0, (short)0, (short)0};
  __syncthreads();
  char* sb = (char*)&stg[w][0];
  unsigned sbase = (unsigned)(uintptr_t)sb;
  f32x4 z4 = {0.f, 0.f, 0.f, 0.f};
#pragma unroll
  for (int g = 0; g < 4; g++) {
    float p0_, p1_, p2_, p3_;
    {
      int jl0 = w * 64 + g * 16 + 4 * gr;
#pragma unroll
      for (int r = 0; r < 4; r++) {
        int jloc = jl0 + r;
        int j = jb * 256 + jloc;
        float d0 = pix - jsx[jloc], d1 = piy - jsy[jloc], d2 = piz - jsz[jloc];
        float mk = (ui == jsu[jloc]) ? 1.f : 0.f;
        float inv = 1.f / (1.f + d0 * d0 + d1 * d1 + d2 * d2);
        float zv = zp[((long)((i & 255) << 8) + jloc) * 16 + c];
        float cbv = cb[j * 16 + c];
        float pv = mk * (d0 * w0c + d1 * w1c + d2 * w2c + inv * wic + wmc) + zv + cbv + cac;
        if (r == 0) p0_ = pv; else if (r == 1) p1_ = pv; else if (r == 2) p2_ = pv; else p3_ = pv;
      }
    }
    char* wp = sb + g * 640 + c * 32 + gr * 8;
    unsigned ra = sbase + (unsigned)(g * 640 + c * 8 + gr * 128);
    *(uint2*)wp = make_uint2(bfpack(fmaxf(p0_, 0.f), fmaxf(p1_, 0.f)),
                             bfpack(fmaxf(p2_, 0.f), fmaxf(p3_, 0.f)));
    s16x4 tr0;
    asm volatile("s_waitcnt lgkmcnt(0)\n\tds_read_b64_tr_b16 %0, %1\n\ts_waitcnt lgkmcnt(0)"
                 : "=v"(tr0) : "v"(ra) : "memory");
    s16x8 a8 = {tr0[0], tr0[1], tr0[2], tr0[3], (short)0, (short)0, (short)0, (short)0};
    f32x4 h1 = __builtin_amdgcn_mfma_f32_16x16x32_bf16(a8, bw0, z4, 0, 0, 0);
    *(uint2*)wp = make_uint2(bfpack(fmaxf(h1[0], 0.f), fmaxf(h1[1], 0.f)),
                             bfpack(fmaxf(h1[2], 0.f), fmaxf(h1[3], 0.f)));
    s16x4 tr1;
    asm volatile("s_waitcnt lgkmcnt(0)\n\tds_read_b64_tr_b16 %0, %1\n\ts_waitcnt lgkmcnt(0)"
                 : "=v"(tr1) : "v"(ra) : "memory");
    s16x8 a8b = {tr1[0], tr1[1], tr1[2], tr1[3], (short)0, (short)0, (short)0, (short)0};
    f32x4 h2 = __builtin_amdgcn_mfma_f32_16x16x32_bf16(a8b, bw1, z4, 0, 0, 0);
    *(uint2*)wp = make_uint2(bfpack(fmaxf(h2[0], 0.f), fmaxf(h2[1], 0.f)),
                             bfpack(fmaxf(h2[2], 0.f), fmaxf(h2[3], 0.f)));
    s16x4 tr2;
    asm volatile("s_waitcnt lgkmcnt(0)\n\tds_read_b64_tr_b16 %0, %1\n\ts_waitcnt lgkmcnt(0)"
                 : "=v"(tr2) : "v"(ra) : "memory");
    s16x8 a8c = {tr2[0], tr2[1], tr2[2], tr2[3], (short)0, (short)0, (short)0, (short)0};
    f32x4 h3 = __builtin_amdgcn_mfma_f32_16x16x32_bf16(a8c, bw2, z4, 0, 0, 0);
    float f0 = p0_ + h3[0], f1 = p1_ + h3[1], f2 = p2_ + h3[2], f3 = p3_ + h3[3];
    {
      int jl0 = w * 64 + g * 16 + 4 * gr;
      long pb = ((long)i * 768 + (long)(jb * 256 + jl0)) * 16 + c;
      pair_out[pb] = f0;
      pair_out[pb + 16] = f1;
      pair_out[pb + 32] = f2;
      pair_out[pb + 48] = f3;
    }
    *(float4*)&pfs[w][g * 264 + c * 16 + 4 * gr] = make_float4(f0, f1, f2, f3);
  }
  asm volatile("s_waitcnt lgkmcnt(0)" ::: "memory");
  int qb = i >> 5;
  int j = jb * 256 + t;
  unsigned jw = (unsigned)(j - (qb * 32 - 48));
  if (jw < 128u) {
    int gt = (t >> 4) & 3, jr = t & 15;
    float v[16];
#pragma unroll
    for (int cc = 0; cc < 16; cc++) v[cc] = pfs[w][gt * 264 + cc * 16 + jr];
    float m = 0.f;
#pragma unroll
    for (int cc = 0; cc < 16; cc++) m += v[cc];
    m *= (1.f / 16.f);
    float vv = 0.f;
#pragma unroll
    for (int cc = 0; cc < 16; cc++) { float d = v[cc] - m; vv += d * d; }
    float rs = rsqrtf(vv * (1.f / 16.f) + 1e-5f);
    float nrm[16];
#pragma unroll
    for (int cc = 0; cc < 16; cc++) nrm[cc] = (v[cc] - m) * rs;
    int qi = i & 31;
#pragma unroll
    for (int bq = 0; bq < 3; bq++) {
      float o0 = kbs[bq * 4 + 0], o1 = kbs[bq * 4 + 1];
      float o2 = kbs[bq * 4 + 2], o3 = kbs[bq * 4 + 3];
#pragma unroll
      for (int k = 0; k < 16; k++) {
        float nv = nrm[k];
        float4 wv = *(float4*)&wgb[bq * 64 + k * 4];
        o0 += nv * wv.x; o1 += nv * wv.y; o2 += nv * wv.z; o3 += nv * wv.w;
      }
      long base = (long)(bq * 96 + qb * 4) * 4096 + (long)qi * 128 + jw;
      biasA[base] = o0;
      biasA[base + 4096] = o1;
      biasA[base + 2 * 4096] = o2;
      biasA[base + 3 * 4096] = o3;
    }
  }
}

// ---------------------------------------------------------------------------
// k_attn2: windowed attention, 16-row q-tiles.  grid 192 (qt*4+h), block 256
__global__ __launch_bounds__(256) void k_attn2(
    const float* __restrict__ qkvg, const float* __restrict__ biasb,
    float* __restrict__ og) {
  int qt = blockIdx.x >> 2, h = blockIdx.x & 3, t = threadIdx.x;
  int i0 = qt * 16;
  int qb32 = qt >> 1;
  int lo = qb32 * 32 - 48;
  int qoff = (qt & 1) * 16;
  __shared__ float qs[16][36];
  __shared__ float ks[128][36];
  __shared__ float vs[128][36];
  __shared__ float L[16][132];
  {
    int e = t * 8;
    int qi = e >> 7, k8 = e & 127;
    const float* bb = &biasb[(long)(qb32 * 4 + h) * 4096 + (long)(qoff + qi) * 128];
#pragma unroll
    for (int m = 0; m < 2; m++) {
      int k4 = k8 + m * 4;
      int j4 = lo + k4;
      float4 bv;
      if (j4 >= 0 && j4 <= 764) bv = *(const float4*)&bb[k4];
      else bv = make_float4(-1e30f, -1e30f, -1e30f, -1e30f);
      *(float4*)&L[qi][k4] = bv;
    }
  }
  if (t < 128) {
    int qi = t >> 3, dq = (t & 7) * 4;
    *(float4*)&qs[qi][dq] = *(const float4*)&qkvg[(i0 + qi) * 512 + h * 32 + dq];
  }
  {
    int kj = t >> 1, dh = (t & 1) * 16;
    int j = lo + kj;
    if (j >= 0 && j < 768) {
      const float4* sk = (const float4*)&qkvg[j * 512 + 128 + h * 32 + dh];
      const float4* sv = (const float4*)&qkvg[j * 512 + 256 + h * 32 + dh];
#pragma unroll
      for (int m = 0; m < 4; m++) {
        *(float4*)&ks[kj][dh + 4 * m] = sk[m];
        *(float4*)&vs[kj][dh + 4 * m] = sv[m];
      }
    } else {
      float4 zz = {0, 0, 0, 0};
#pragma unroll
      for (int m = 0; m < 4; m++) {
        *(float4*)&ks[kj][dh + 4 * m] = zz;
        *(float4*)&vs[kj][dh + 4 * m] = zz;
      }
    }
  }
  __syncthreads();
  const float scale = 0.17677669529663687f;
  {
    int qi = t & 15, kb = t >> 4;
    float4 qr[8];
#pragma unroll
    for (int m = 0; m < 8; m++) qr[m] = *(float4*)&qs[qi][m * 4];
#pragma unroll
    for (int kk = 0; kk < 8; kk++) {
      int kj = kb * 8 + kk;
      float acc = 0.f;
#pragma unroll
      for (int m = 0; m < 8; m++) {
        float4 kv = *(float4*)&ks[kj][m * 4];
        acc += qr[m].x * kv.x + qr[m].y * kv.y + qr[m].z * kv.z + qr[m].w * kv.w;
      }
      L[qi][kj] += acc * scale;
    }
  }
  __syncthreads();
  int qi = t >> 4, sg = t & 15;
  float mx = -1e30f;
#pragma unroll
  for (int k2 = 0; k2 < 8; k2++) mx = fmaxf(mx, L[qi][sg * 8 + k2]);
#pragma unroll
  for (int o = 1; o < 16; o <<= 1) mx = fmaxf(mx, __shfl_xor(mx, o));
  float sum = 0.f;
#pragma unroll
  for (int k2 = 0; k2 < 8; k2++) {
    int kj = sg * 8 + k2;
    float e = __expf(L[qi][kj] - mx);
    L[qi][kj] = e;
    sum += e;
  }
#pragma unroll
  for (int o = 1; o < 16; o <<= 1) sum += __shfl_xor(sum, o);
  float rden = 1.f / sum;
  __syncthreads();
  {
    int d2 = (t & 15) * 2;
    float a0 = 0.f, a1 = 0.f;
#pragma unroll 8
    for (int kj = 0; kj < 128; kj++) {
      float p = L[qi][kj];
      float2 v = *(float2*)&vs[kj][d2];
      a0 += p * v.x; a1 += p * v.y;
    }
    int i = i0 + qi;
    float2 gr = *(const float2*)&qkvg[i * 512 + 384 + h * 32 + d2];
    float2 o2;
    o2.x = a0 * rden * sigmoidf_(gr.x);
    o2.y = a1 * rden * sigmoidf_(gr.y);
    *(float2*)&og[i * 128 + h * 32 + d2] = o2;
  }
}

// ---------------------------------------------------------------------------
// k_fusedT<MODE>: x += og@Wo; a=LN(x); x += relu(a@Wt1)@Wt2; then
//  MODE 1: qkvg_next = LN_next(x) @ [Wq|Wk|Wv|Wg]
//  MODE 2: qout = relu(x@W_proj), a_out = mean (k_final fused)
// grid 256 (3 rows/block, 1/CU), block 384.  (all GEMM loops: unroll 8)
template <int MODE>
__global__ __launch_bounds__(384) void k_fusedT(
    const float* __restrict__ og, const float* __restrict__ Wo,
    const float* __restrict__ g2, const float* __restrict__ b2,
    const float* __restrict__ Wt1, const float* __restrict__ Wt2,
    float* __restrict__ x,
    const float* __restrict__ lng_n, const float* __restrict__ lnb_n,
    const float* __restrict__ Wq, const float* __restrict__ Wk,
    const float* __restrict__ Wv, const float* __restrict__ Wg,
    float* __restrict__ qkvg, const float* __restrict__ W_proj,
    float* __restrict__ out) {
  int t = threadIdx.x;
  int r0 = blockIdx.x * 3;
  __shared__ float osr[3][128];
  __shared__ float xns[3][128];
  __shared__ float asr[3][128];
  __shared__ float hs[3][512];
  __shared__ float part[4][3][128];
  __shared__ float red[12];
  {
    int rr = t >> 7, c = t & 127;
    osr[rr][c] = og[(r0 + rr) * 128 + c];
    xns[rr][c] = x[(r0 + rr) * 128 + c];
  }
  __syncthreads();
  {
    int c4 = (t & 31) * 4, row = (t >> 5) % 3, q = t / 96;
    int k0 = q * 32;
    float a0 = 0.f, a1 = 0.f, a2 = 0.f, a3 = 0.f;
#pragma unroll 8
    for (int kk = 0; kk < 32; kk++) {
      int k = k0 + kk;
      float4 w = *(const float4*)&Wo[k * 128 + c4];
      float av = osr[row][k];
      a0 += av * w.x; a1 += av * w.y; a2 += av * w.z; a3 += av * w.w;
    }
    *(float4*)&part[q][row][c4] = make_float4(a0, a1, a2, a3);
  }
  __syncthreads();
  {
    int rr = t >> 7, c = t & 127;
    float xv = xns[rr][c] + part[0][rr][c] + part[1][rr][c] + part[2][rr][c] + part[3][rr][c];
    float ps = xv, pq = xv * xv;
#pragma unroll
    for (int o = 1; o < 64; o <<= 1) { ps += __shfl_xor(ps, o); pq += __shfl_xor(pq, o); }
    int wv = t >> 6;
    if ((t & 63) == 0) { red[wv] = ps; red[6 + wv] = pq; }
    __syncthreads();
    float mean = (red[2 * rr] + red[2 * rr + 1]) * (1.f / 128.f);
    float var = (red[6 + 2 * rr] + red[6 + 2 * rr + 1]) * (1.f / 128.f) - mean * mean;
    float rstd = rsqrtf(var + 1e-5f);
    xns[rr][c] = xv;
    asr[rr][c] = (xv - mean) * rstd * g2[c] + b2[c];
  }
  __syncthreads();
  {
    int c4 = (t & 127) * 4, row = t >> 7;
    float a0 = 0.f, a1 = 0.f, a2 = 0.f, a3 = 0.f;
#pragma unroll 8
    for (int k = 0; k < 128; k++) {
      float4 w = *(const float4*)&Wt1[k * 512 + c4];
      float av = asr[row][k];
      a0 += av * w.x; a1 += av * w.y; a2 += av * w.z; a3 += av * w.w;
    }
    *(float4*)&hs[row][c4] = make_float4(fmaxf(a0, 0.f), fmaxf(a1, 0.f),
                                         fmaxf(a2, 0.f), fmaxf(a3, 0.f));
  }
  __syncthreads();
  {
    int c4 = (t & 31) * 4, row = (t >> 5) % 3, q = t / 96;
    int k0 = q * 128;
    float a0 = 0.f, a1 = 0.f, a2 = 0.f, a3 = 0.f;
#pragma unroll 8
    for (int kk = 0; kk < 128; kk++) {
      int k = k0 + kk;
      float4 w = *(const float4*)&Wt2[k * 128 + c4];
      float hv = hs[row][k];
      a0 += hv * w.x; a1 += hv * w.y; a2 += hv * w.z; a3 += hv * w.w;
    }
    *(float4*)&part[q][row][c4] = make_float4(a0, a1, a2, a3);
  }
  __syncthreads();
  {
    int rr = t >> 7, c = t & 127;
    float xf = xns[rr][c] + part[0][rr][c] + part[1][rr][c] +
               part[2][rr][c] + part[3][rr][c];
    x[(r0 + rr) * 128 + c] = xf;
    xns[rr][c] = xf;
  }
  if (MODE == 1) {
    __syncthreads();
    {
      int rr = t >> 7, c = t & 127;
      float xv = xns[rr][c];
      float ps = xv, pq = xv * xv;
#pragma unroll
      for (int o = 1; o < 64; o <<= 1) { ps += __shfl_xor(ps, o); pq += __shfl_xor(pq, o); }
      int wv = t >> 6;
      if ((t & 63) == 0) { red[wv] = ps; red[6 + wv] = pq; }
      __syncthreads();
      float mean = (red[2 * rr] + red[2 * rr + 1]) * (1.f / 128.f);
      float var = (red[6 + 2 * rr] + red[6 + 2 * rr + 1]) * (1.f / 128.f) - mean * mean;
      float rstd = rsqrtf(var + 1e-5f);
      asr[rr][c] = (xv - mean) * rstd * lng_n[c] + lnb_n[c];
    }
    __syncthreads();
    {
      int c4 = (t & 127) * 4, row = t >> 7;
      int mtx = c4 >> 7, lc = c4 & 127;
      const float* Wm = (mtx == 0) ? Wq : (mtx == 1) ? Wk : (mtx == 2) ? Wv : Wg;
      float a0 = 0.f, a1 = 0.f, a2 = 0.f, a3 = 0.f;
#pragma unroll 8
      for (int k = 0; k < 128; k++) {
        float4 w = *(const float4*)&Wm[k * 128 + lc];
        float av = asr[row][k];
        a0 += av * w.x; a1 += av * w.y; a2 += av * w.z; a3 += av * w.w;
      }
      *(float4*)&qkvg[(r0 + row) * 512 + c4] = make_float4(a0, a1, a2, a3);
    }
  }
  if (MODE == 2) {
    __syncthreads();
    int tk = blockIdx.x;
    float a0 = 0.f, a1 = 0.f, a2 = 0.f;
#pragma unroll 8
    for (int k = 0; k < 128; k++) {
      float w = W_proj[k * 384 + t];
      a0 += xns[0][k] * w; a1 += xns[1][k] * w; a2 += xns[2][k] * w;
    }
    a0 = fmaxf(a0, 0.f); a1 = fmaxf(a1, 0.f); a2 = fmaxf(a2, 0.f);
    out[98304 + (tk * 3 + 0) * 384 + t] = a0;
    out[98304 + (tk * 3 + 1) * 384 + t] = a1;
    out[98304 + (tk * 3 + 2) * 384 + t] = a2;
    out[tk * 384 + t] = (a0 + a1 + a2) * (1.f / 3.f);
  }
}

// ---------------------------------------------------------------------------
extern "C" void kernel_launch(void* const* d_in, const int* in_sizes, int n_in,
                              void* d_out, int out_size, void* d_ws, size_t ws_size,
                              hipStream_t stream) {
  const float* ref_pos  = (const float*)d_in[0];
  const int*   uid      = (const int*)d_in[1];
  const float* r        = (const float*)d_in[2];
  const float* s        = (const float*)d_in[3];
  const float* z        = (const float*)d_in[4];
  const float* W_pos    = (const float*)d_in[5];
  const float* Wpo      = (const float*)d_in[6];
  const float* Wisd     = (const float*)d_in[7];
  const float* Wmask    = (const float*)d_in[8];
  const float* Wca      = (const float*)d_in[9];
  const float* Wcb      = (const float*)d_in[10];
  const float* ln_s_g   = (const float*)d_in[11];
  const float* ln_s_b   = (const float*)d_in[12];
  const float* W_single = (const float*)d_in[13];
  const float* ln_z_g   = (const float*)d_in[14];
  const float* ln_z_b   = (const float*)d_in[15];
  const float* W_pair   = (const float*)d_in[16];
  const float* W_noisy  = (const float*)d_in[17];
  const float* W_mlp1   = (const float*)d_in[18];
  const float* W_mlp2   = (const float*)d_in[19];
  const float* W_mlp3   = (const float*)d_in[20];
  const float* at_ln_g  = (const float*)d_in[21];
  const float* at_ln_b  = (const float*)d_in[22];
  const float* at_Wq    = (const float*)d_in[23];
  const float* at_Wk    = (const float*)d_in[24];
  const float* at_Wv    = (const float*)d_in[25];
  const float* at_Wg    = (const float*)d_in[26];
  const float* at_lnp_g = (const float*)d_in[27];
  const float* at_lnp_b = (const float*)d_in[28];
  const float* at_Wb    = (const float*)d_in[29];
  const float* at_Wo    = (const float*)d_in[30];
  const float* at_ln2_g = (const float*)d_in[31];
  const float* at_ln2_b = (const float*)d_in[32];
  const float* at_Wt1   = (const float*)d_in[33];
  const float* at_Wt2   = (const float*)d_in[34];
  const float* W_proj   = (const float*)d_in[35];
  float* out = (float*)d_out;
  float* W = (float*)d_ws;
  float* x     = W;                 //   98304
  float* ca    = W + 98304;         //   12288
  float* cb    = W + 110592;        //   12288
  float* zp    = W + 122880;        // 1048576
  float* biasA = W + 1171456;       // 1179648
  float* qkvg  = W + 2351104;       //  393216
  float* og    = W + 2744320;       //   98304

  k_front<<<4352, 256, 0, stream>>>(z, ln_z_g, ln_z_b, W_pair, zp,
                                    s, ln_s_g, ln_s_b, W_single, ref_pos, r,
                                    W_pos, W_noisy, Wca, Wcb,
                                    out + 393216, x, ca, cb);
  k_pairq<<<2688, 256, 0, stream>>>(ref_pos, uid, Wpo, Wisd, Wmask, W_mlp1, W_mlp2,
                                    W_mlp3, zp, ca, cb, at_lnp_g, at_lnp_b, at_Wb,
                                    out + 491520, biasA,
                                    x, at_ln_g, at_ln_b, at_Wq, at_Wk, at_Wv, at_Wg,
                                    qkvg);
  // layer 0
  k_attn2<<<192, 256, 0, stream>>>(qkvg, biasA, og);
  k_fusedT<1><<<256, 384, 0, stream>>>(og, at_Wo, at_ln2_g, at_ln2_b, at_Wt1, at_Wt2, x,
                                       at_ln_g + 128, at_ln_b + 128,
                                       at_Wq + 16384, at_Wk + 16384,
                                       at_Wv + 16384, at_Wg + 16384, qkvg,
                                       nullptr, nullptr);
  // layer 1
  k_attn2<<<192, 256, 0, stream>>>(qkvg, biasA + 393216, og);
  k_fusedT<1><<<256, 384, 0, stream>>>(og, at_Wo + 16384, at_ln2_g + 128, at_ln2_b + 128,
                                       at_Wt1 + 65536, at_Wt2 + 65536, x,
                                       at_ln_g + 256, at_ln_b + 256,
                                       at_Wq + 32768, at_Wk + 32768,
                                       at_Wv + 32768, at_Wg + 32768, qkvg,
                                       nullptr, nullptr);
  // layer 2
  k_attn2<<<192, 256, 0, stream>>>(qkvg, biasA + 786432, og);
  k_fusedT<2><<<256, 384, 0, stream>>>(og, at_Wo + 32768, at_ln2_g + 256, at_ln2_b + 256,
                                       at_Wt1 + 131072, at_Wt2 + 131072, x,
                                       nullptr, nullptr, nullptr, nullptr,
                                       nullptr, nullptr, nullptr, W_proj, out);
}

// Round 16
// 145.344 us; speedup vs baseline: 1.4316x; 1.0725x over previous
//
#include <hip/hip_runtime.h>
#include <math.h>

// N=768 atoms, T=256 tokens, CA=128, CP=16, CZ=128, CS=384, CT=384, H=4, DH=32
// d_out: a_out[256*384]@0, qout[768*384]@98304, c[768*128]@393216, pair[768*768*16]@491520

__device__ __forceinline__ float sigmoidf_(float v) { return 1.f / (1.f + __expf(-v)); }

typedef __attribute__((ext_vector_type(4))) short s16x4;
typedef __attribute__((ext_vector_type(8))) short s16x8;
typedef __attribute__((ext_vector_type(4))) float f32x4;

__device__ __forceinline__ unsigned bfpack(float a, float b) {
  return (__float_as_uint(a) >> 16) | (__float_as_uint(b) & 0xFFFF0000u);
}
__device__ __forceinline__ short bf1(float a) { return (short)(__float_as_uint(a) >> 16); }

// ---------------------------------------------------------------------------
// k_front: bid<1024 -> zp via MFMA (64 z-rows/block) ; bid>=1024 -> tokatoms
// grid 1280, block 256.  Shared pool 5392 floats (21.6 KB).
__global__ __launch_bounds__(256) void k_front(
    const float* __restrict__ z, const float* __restrict__ zg,
    const float* __restrict__ zlb, const float* __restrict__ W_pair,
    float* __restrict__ zp,
    const float* __restrict__ s, const float* __restrict__ g,
    const float* __restrict__ b, const float* __restrict__ W_single,
    const float* __restrict__ ref_pos, const float* __restrict__ r,
    const float* __restrict__ W_pos, const float* __restrict__ W_noisy,
    const float* __restrict__ Wca, const float* __restrict__ Wcb,
    float* __restrict__ c_out, float* __restrict__ x,
    float* __restrict__ ca, float* __restrict__ cb) {
  __shared__ __align__(128) float sm[5392];
  int t = threadIdx.x;
  int bid = blockIdx.x;
  if (bid < 1024) {
    // ---------- zp: LN(z) @ Wg via MFMA; wave owns a 16-row tile ----------
    float* bcp = sm + 5120;   // [16 kseg][16 ch]
    float* Bc = sm + 5376;    // [16]
    // Bc = zlb @ W_pair  (block-cooperative)
    {
      int ch = t & 15, kseg = t >> 4;
      float a = 0.f;
#pragma unroll
      for (int e = 0; e < 8; e++) {
        int k = kseg * 8 + e;
        a += zlb[k] * W_pair[k * 16 + ch];
      }
      bcp[kseg * 16 + ch] = a;
    }
    __syncthreads();
    if (t < 16) {
      float a = 0.f;
#pragma unroll
      for (int kseg = 0; kseg < 16; kseg++) a += bcp[kseg * 16 + t];
      Bc[t] = a;
    }
    __syncthreads();
    int w = t >> 6, l = t & 63;
    int kb = l & 15, rg = l >> 4;
    int row0 = bid * 64 + w * 16;
    char* stgw = (char*)(sm + w * 1280);   // 5120 B per wave
    // load z rows 4rg..+3, cols 8kb..+7 ; LN per row
    float4 za[4], zb[4];
    float m_[4], rs_[4];
#pragma unroll
    for (int rr = 0; rr < 4; rr++) {
      long base = (long)(row0 + rg * 4 + rr) * 128 + kb * 8;
      za[rr] = *(const float4*)&z[base];
      zb[rr] = *(const float4*)&z[base + 4];
      float ps = za[rr].x + za[rr].y + za[rr].z + za[rr].w +
                 zb[rr].x + zb[rr].y + zb[rr].z + zb[rr].w;
      float pq = za[rr].x * za[rr].x + za[rr].y * za[rr].y + za[rr].z * za[rr].z +
                 za[rr].w * za[rr].w + zb[rr].x * zb[rr].x + zb[rr].y * zb[rr].y +
                 zb[rr].z * zb[rr].z + zb[rr].w * zb[rr].w;
#pragma unroll
      for (int o = 1; o < 16; o <<= 1) { ps += __shfl_xor(ps, o); pq += __shfl_xor(pq, o); }
      m_[rr] = ps * (1.f / 128.f);
      rs_[rr] = rsqrtf(pq * (1.f / 128.f) - m_[rr] * m_[rr] + 1e-5f);
    }
    // normalize + pack rows-of-4 per k, write into pairM-style staging
    {
      int kc = kb >> 1;
      int cbase = (kb & 1) * 8;
#pragma unroll
      for (int e = 0; e < 8; e++) {
        float a0 = ((e < 4 ? (&za[0].x)[e] : (&zb[0].x)[e - 4]) - m_[0]) * rs_[0];
        float a1 = ((e < 4 ? (&za[1].x)[e] : (&zb[1].x)[e - 4]) - m_[1]) * rs_[1];
        float a2 = ((e < 4 ? (&za[2].x)[e] : (&zb[2].x)[e - 4]) - m_[2]) * rs_[2];
        float a3 = ((e < 4 ? (&za[3].x)[e] : (&zb[3].x)[e - 4]) - m_[3]) * rs_[3];
        char* wp = stgw + kc * 640 + (cbase + e) * 32 + rg * 8;
        *(uint2*)wp = make_uint2(bfpack(a0, a1), bfpack(a2, a3));
      }
    }
    // B fragments: bw[kc][e] = Wg[kc*16 + 4*rg + e][c], c = l&15
    int c = l & 15;
    s16x8 bw[8];
#pragma unroll
    for (int kc = 0; kc < 8; kc++) {
      short e0, e1, e2, e3;
      {
        int kk = kc * 16 + 4 * rg;
        e0 = bf1(zg[kk] * W_pair[kk * 16 + c]);
        e1 = bf1(zg[kk + 1] * W_pair[(kk + 1) * 16 + c]);
        e2 = bf1(zg[kk + 2] * W_pair[(kk + 2) * 16 + c]);
        e3 = bf1(zg[kk + 3] * W_pair[(kk + 3) * 16 + c]);
      }
      bw[kc] = s16x8{e0, e1, e2, e3, (short)0, (short)0, (short)0, (short)0};
    }
    unsigned sbase = (unsigned)(uintptr_t)stgw;
    f32x4 acc = {0.f, 0.f, 0.f, 0.f};
#pragma unroll
    for (int kc = 0; kc < 8; kc++) {
      unsigned ra = sbase + (unsigned)(kc * 640 + c * 8 + rg * 128);
      s16x4 tr;
      asm volatile("s_waitcnt lgkmcnt(0)\n\tds_read_b64_tr_b16 %0, %1\n\ts_waitcnt lgkmcnt(0)"
                   : "=v"(tr) : "v"(ra) : "memory");
      s16x8 a8 = {tr[0], tr[1], tr[2], tr[3], (short)0, (short)0, (short)0, (short)0};
      acc = __builtin_amdgcn_mfma_f32_16x16x32_bf16(a8, bw[kc], acc, 0, 0, 0);
    }
    float bc = Bc[c];
#pragma unroll
    for (int rr = 0; rr < 4; rr++) {
      int row = row0 + rg * 4 + rr;
      zp[(long)row * 16 + c] = acc[rr] + bc;
    }
  } else {
    // ---------------- tokatoms (guards t<128; barriers uniform) ------------
    int tok = bid - 1024;
    float* sln = sm;            // [384]
    float* ws = sm + 384;       // [32*128]
    float* red = sm + 4480;     // [4]
    float* rc = sm + 4488;      // [128]
    float v0 = 0.f, v1 = 0.f, v2 = 0.f;
    if (t < 128) {
      v0 = s[tok * 384 + t]; v1 = s[tok * 384 + 128 + t]; v2 = s[tok * 384 + 256 + t];
      float ps = v0 + v1 + v2, pq = v0 * v0 + v1 * v1 + v2 * v2;
#pragma unroll
      for (int o = 1; o < 64; o <<= 1) { ps += __shfl_xor(ps, o); pq += __shfl_xor(pq, o); }
      if ((t & 63) == 0) { red[t >> 6] = ps; red[2 + (t >> 6)] = pq; }
    }
    __syncthreads();
    float ctv = 0.f;
    if (t < 128) {
      float mean = (red[0] + red[1]) * (1.f / 384.f);
      float var = (red[2] + red[3]) * (1.f / 384.f) - mean * mean;
      float rstd = rsqrtf(var + 1e-5f);
      sln[t] = (v0 - mean) * rstd * g[t] + b[t];
      sln[128 + t] = (v1 - mean) * rstd * g[128 + t] + b[128 + t];
      sln[256 + t] = (v2 - mean) * rstd * g[256 + t] + b[256 + t];
    }
    for (int c0 = 0; c0 < 384; c0 += 32) {
      __syncthreads();
#pragma unroll
      for (int m = 0; m < 4; m++) {
        int idx = (t + 256 * m) * 4;
        *(float4*)&ws[idx] = *(const float4*)&W_single[c0 * 128 + idx];
      }
      __syncthreads();
      if (t < 128) {
#pragma unroll 8
        for (int kk = 0; kk < 32; kk++) ctv += sln[c0 + kk] * ws[kk * 128 + t];
      }
    }
    float wp0 = 0.f, wp1 = 0.f, wp2 = 0.f, wn0 = 0.f, wn1 = 0.f, wn2 = 0.f;
    if (t < 128) {
      wp0 = W_pos[t]; wp1 = W_pos[128 + t]; wp2 = W_pos[256 + t];
      wn0 = W_noisy[t]; wn1 = W_noisy[128 + t]; wn2 = W_noisy[256 + t];
    }
#pragma unroll
    for (int a = 0; a < 3; a++) {
      int i = tok + 256 * a;
      float cc = 0.f;
      if (t < 128) {
        float p0 = ref_pos[i * 3], p1 = ref_pos[i * 3 + 1], p2 = ref_pos[i * 3 + 2];
        float r0 = r[i * 3], r1 = r[i * 3 + 1], r2 = r[i * 3 + 2];
        float c0 = p0 * wp0 + p1 * wp1 + p2 * wp2;
        x[i * 128 + t] = c0 + r0 * wn0 + r1 * wn1 + r2 * wn2;
        cc = c0 + ctv;
        c_out[i * 128 + t] = cc;
      }
      __syncthreads();
      if (t < 128) rc[t] = fmaxf(cc, 0.f);
      __syncthreads();
      if (t < 128) {
        int out_id = t >> 2, q = t & 3;
        const float* Wm = (out_id < 16) ? Wca : Wcb;
        int ch = out_id & 15;
        float acc = 0.f;
#pragma unroll
        for (int kk = 0; kk < 32; kk++) { int k = q * 32 + kk; acc += rc[k] * Wm[k * 16 + ch]; }
        acc += __shfl_xor(acc, 1);
        acc += __shfl_xor(acc, 2);
        if (q == 0) { if (out_id < 16) ca[i * 16 + ch] = acc; else cb[i * 16 + ch] = acc; }
      }
    }
  }
}

// ---------------------------------------------------------------------------
// k_pairq: bid<2304 -> pairM ; bid>=2304 -> qkvg layer-0 (direct weights)
// grid 2688, block 256
__global__ __launch_bounds__(256) void k_pairq(
    const float* __restrict__ ref_pos, const int* __restrict__ uid,
    const float* __restrict__ Wpo, const float* __restrict__ Wisd,
    const float* __restrict__ Wmask, const float* __restrict__ W1,
    const float* __restrict__ W2, const float* __restrict__ W3,
    const float* __restrict__ zp, const float* __restrict__ ca,
    const float* __restrict__ cb, const float* __restrict__ lnp_g,
    const float* __restrict__ lnp_b, const float* __restrict__ Wb,
    float* __restrict__ pair_out, float* __restrict__ biasA,
    const float* __restrict__ x, const float* __restrict__ lng,
    const float* __restrict__ lnb, const float* __restrict__ Wq,
    const float* __restrict__ Wk, const float* __restrict__ Wv,
    const float* __restrict__ Wg, float* __restrict__ qkvg) {
  __shared__ float jsx[256], jsy[256], jsz[256];
  __shared__ int jsu[256];
  __shared__ __align__(128) short stg[4][1280];
  __shared__ __align__(16) float pfs[4][1056];
  __shared__ float wgb[192];
  __shared__ float kbs[12];
  int t = threadIdx.x;
  int bid = blockIdx.x;
  if (bid >= 2304) {
    int r0 = (bid - 2304) * 2;
    float* asr_ = jsx;
    float* red_ = jsy;
    int row = t >> 7, c = t & 127;
    float xv = x[(r0 + row) * 128 + c];
    {
      float ps = xv, pq = xv * xv;
#pragma unroll
      for (int o = 1; o < 64; o <<= 1) { ps += __shfl_xor(ps, o); pq += __shfl_xor(pq, o); }
      int wv = t >> 6;
      if ((t & 63) == 0) { red_[wv] = ps; red_[4 + wv] = pq; }
      __syncthreads();
      float mean = (red_[2 * row] + red_[2 * row + 1]) * (1.f / 128.f);
      float var = (red_[4 + 2 * row] + red_[4 + 2 * row + 1]) * (1.f / 128.f) - mean * mean;
      float rstd = rsqrtf(var + 1e-5f);
      asr_[row * 128 + c] = (xv - mean) * rstd * lng[c] + lnb[c];
    }
    __syncthreads();
    {
      int c4 = (t & 127) * 4, row2 = t >> 7;
      int mtx = c4 >> 7, lc = c4 & 127;
      const float* Wm = (mtx == 0) ? Wq : (mtx == 1) ? Wk : (mtx == 2) ? Wv : Wg;
      float a0 = 0.f, a1 = 0.f, a2 = 0.f, a3 = 0.f;
#pragma unroll 8
      for (int k = 0; k < 128; k++) {
        float4 w = *(const float4*)&Wm[k * 128 + lc];
        float av = asr_[row2 * 128 + k];
        a0 += av * w.x; a1 += av * w.y; a2 += av * w.z; a3 += av * w.w;
      }
      *(float4*)&qkvg[(r0 + row2) * 512 + c4] = make_float4(a0, a1, a2, a3);
    }
    return;
  }
  int i = bid / 3, jb = bid % 3;
  int jg = jb * 256 + t;
  jsx[t] = ref_pos[jg * 3];
  jsy[t] = ref_pos[jg * 3 + 1];
  jsz[t] = ref_pos[jg * 3 + 2];
  jsu[t] = uid[jg];
  if (t >= 64) {
    int e = t - 64;
    if (e < 192) {
      int bq = e >> 6, k = (e >> 2) & 15, h = e & 3;
      wgb[e] = lnp_g[bq * 16 + k] * Wb[bq * 64 + k * 4 + h];
    }
  }
  if (t >= 48 && t < 60) {
    int e = t - 48, bq = e >> 2, h = e & 3;
    float a = 0.f;
#pragma unroll
    for (int cc = 0; cc < 16; cc++) a += lnp_b[bq * 16 + cc] * Wb[bq * 64 + cc * 4 + h];
    kbs[e] = a;
  }
  int w = t >> 6, l = t & 63;
  int c = l & 15, gr = l >> 4;
  float pix = ref_pos[i * 3], piy = ref_pos[i * 3 + 1], piz = ref_pos[i * 3 + 2];
  int ui = uid[i];
  float w0c = Wpo[c], w1c = Wpo[16 + c], w2c = Wpo[32 + c];
  float wic = Wisd[c], wmc = Wmask[c], cac = ca[i * 16 + c];
  s16x8 bw0 = {bf1(W1[(4 * gr + 0) * 16 + c]), bf1(W1[(4 * gr + 1) * 16 + c]),
               bf1(W1[(4 * gr + 2) * 16 + c]), bf1(W1[(4 * gr + 3) * 16 + c]),
               (short)0, (short)0, (short)0, (short)0};
  s16x8 bw1 = {bf1(W2[(4 * gr + 0) * 16 + c]), bf1(W2[(4 * gr + 1) * 16 + c]),
               bf1(W2[(4 * gr + 2) * 16 + c]), bf1(W2[(4 * gr + 3) * 16 + c]),
               (short)0, (short)0, (short)0, (short)0};
  s16x8 bw2 = {bf1(W3[(4 * gr + 0) * 16 + c]), bf1(W3[(4 * gr + 1) * 16 + c]),
               bf1(W3[(4 * gr + 2) * 16 + c]), bf1(W3[(4 * gr + 3) * 16 + c]),
               (short)0, (short)0, (short)0, (short)0};
  __syncthreads();
  char* sb = (char*)&stg[w][0];
  unsigned sbase = (unsigned)(uintptr_t)sb;
  f32x4 z4 = {0.f, 0.f, 0.f, 0.f};
#pragma unroll
  for (int g = 0; g < 4; g++) {
    float p0_, p1_, p2_, p3_;
    {
      int jl0 = w * 64 + g * 16 + 4 * gr;
#pragma unroll
      for (int r = 0; r < 4; r++) {
        int jloc = jl0 + r;
        int j = jb * 256 + jloc;
        float d0 = pix - jsx[jloc], d1 = piy - jsy[jloc], d2 = piz - jsz[jloc];
        float mk = (ui == jsu[jloc]) ? 1.f : 0.f;
        float inv = 1.f / (1.f + d0 * d0 + d1 * d1 + d2 * d2);
        float zv = zp[((long)((i & 255) << 8) + jloc) * 16 + c];
        float cbv = cb[j * 16 + c];
        float pv = mk * (d0 * w0c + d1 * w1c + d2 * w2c + inv * wic + wmc) + zv + cbv + cac;
        if (r == 0) p0_ = pv; else if (r == 1) p1_ = pv; else if (r == 2) p2_ = pv; else p3_ = pv;
      }
    }
    char* wp = sb + g * 640 + c * 32 + gr * 8;
    unsigned ra = sbase + (unsigned)(g * 640 + c * 8 + gr * 128);
    *(uint2*)wp = make_uint2(bfpack(fmaxf(p0_, 0.f), fmaxf(p1_, 0.f)),
                             bfpack(fmaxf(p2_, 0.f), fmaxf(p3_, 0.f)));
    s16x4 tr0;
    asm volatile("s_waitcnt lgkmcnt(0)\n\tds_read_b64_tr_b16 %0, %1\n\ts_waitcnt lgkmcnt(0)"
                 : "=v"(tr0) : "v"(ra) : "memory");
    s16x8 a8 = {tr0[0], tr0[1], tr0[2], tr0[3], (short)0, (short)0, (short)0, (short)0};
    f32x4 h1 = __builtin_amdgcn_mfma_f32_16x16x32_bf16(a8, bw0, z4, 0, 0, 0);
    *(uint2*)wp = make_uint2(bfpack(fmaxf(h1[0], 0.f), fmaxf(h1[1], 0.f)),
                             bfpack(fmaxf(h1[2], 0.f), fmaxf(h1[3], 0.f)));
    s16x4 tr1;
    asm volatile("s_waitcnt lgkmcnt(0)\n\tds_read_b64_tr_b16 %0, %1\n\ts_waitcnt lgkmcnt(0)"
                 : "=v"(tr1) : "v"(ra) : "memory");
    s16x8 a8b = {tr1[0], tr1[1], tr1[2], tr1[3], (short)0, (short)0, (short)0, (short)0};
    f32x4 h2 = __builtin_amdgcn_mfma_f32_16x16x32_bf16(a8b, bw1, z4, 0, 0, 0);
    *(uint2*)wp = make_uint2(bfpack(fmaxf(h2[0], 0.f), fmaxf(h2[1], 0.f)),
                             bfpack(fmaxf(h2[2], 0.f), fmaxf(h2[3], 0.f)));
    s16x4 tr2;
    asm volatile("s_waitcnt lgkmcnt(0)\n\tds_read_b64_tr_b16 %0, %1\n\ts_waitcnt lgkmcnt(0)"
                 : "=v"(tr2) : "v"(ra) : "memory");
    s16x8 a8c = {tr2[0], tr2[1], tr2[2], tr2[3], (short)0, (short)0, (short)0, (short)0};
    f32x4 h3 = __builtin_amdgcn_mfma_f32_16x16x32_bf16(a8c, bw2, z4, 0, 0, 0);
    float f0 = p0_ + h3[0], f1 = p1_ + h3[1], f2 = p2_ + h3[2], f3 = p3_ + h3[3];
    {
      int jl0 = w * 64 + g * 16 + 4 * gr;
      long pb = ((long)i * 768 + (long)(jb * 256 + jl0)) * 16 + c;
      pair_out[pb] = f0;
      pair_out[pb + 16] = f1;
      pair_out[pb + 32] = f2;
      pair_out[pb + 48] = f3;
    }
    *(float4*)&pfs[w][g * 264 + c * 16 + 4 * gr] = make_float4(f0, f1, f2, f3);
  }
  asm volatile("s_waitcnt lgkmcnt(0)" ::: "memory");
  int qb = i >> 5;
  int j = jb * 256 + t;
  unsigned jw = (unsigned)(j - (qb * 32 - 48));
  if (jw < 128u) {
    int gt = (t >> 4) & 3, jr = t & 15;
    float v[16];
#pragma unroll
    for (int cc = 0; cc < 16; cc++) v[cc] = pfs[w][gt * 264 + cc * 16 + jr];
    float m = 0.f;
#pragma unroll
    for (int cc = 0; cc < 16; cc++) m += v[cc];
    m *= (1.f / 16.f);
    float vv = 0.f;
#pragma unroll
    for (int cc = 0; cc < 16; cc++) { float d = v[cc] - m; vv += d * d; }
    float rs = rsqrtf(vv * (1.f / 16.f) + 1e-5f);
    float nrm[16];
#pragma unroll
    for (int cc = 0; cc < 16; cc++) nrm[cc] = (v[cc] - m) * rs;
    int qi = i & 31;
#pragma unroll
    for (int bq = 0; bq < 3; bq++) {
      float o0 = kbs[bq * 4 + 0], o1 = kbs[bq * 4 + 1];
      float o2 = kbs[bq * 4 + 2], o3 = kbs[bq * 4 + 3];
#pragma unroll
      for (int k = 0; k < 16; k++) {
        float nv = nrm[k];
        float4 wv = *(float4*)&wgb[bq * 64 + k * 4];
        o0 += nv * wv.x; o1 += nv * wv.y; o2 += nv * wv.z; o3 += nv * wv.w;
      }
      long base = (long)(bq * 96 + qb * 4) * 4096 + (long)qi * 128 + jw;
      biasA[base] = o0;
      biasA[base + 4096] = o1;
      biasA[base + 2 * 4096] = o2;
      biasA[base + 3 * 4096] = o3;
    }
  }
}

// ---------------------------------------------------------------------------
// k_attn2: windowed attention, 16-row q-tiles.  grid 192 (qt*4+h), block 256
__global__ __launch_bounds__(256) void k_attn2(
    const float* __restrict__ qkvg, const float* __restrict__ biasb,
    float* __restrict__ og) {
  int qt = blockIdx.x >> 2, h = blockIdx.x & 3, t = threadIdx.x;
  int i0 = qt * 16;
  int qb32 = qt >> 1;
  int lo = qb32 * 32 - 48;
  int qoff = (qt & 1) * 16;
  __shared__ float qs[16][36];
  __shared__ float ks[128][36];
  __shared__ float vs[128][36];
  __shared__ float L[16][132];
  {
    int e = t * 8;
    int qi = e >> 7, k8 = e & 127;
    const float* bb = &biasb[(long)(qb32 * 4 + h) * 4096 + (long)(qoff + qi) * 128];
#pragma unroll
    for (int m = 0; m < 2; m++) {
      int k4 = k8 + m * 4;
      int j4 = lo + k4;
      float4 bv;
      if (j4 >= 0 && j4 <= 764) bv = *(const float4*)&bb[k4];
      else bv = make_float4(-1e30f, -1e30f, -1e30f, -1e30f);
      *(float4*)&L[qi][k4] = bv;
    }
  }
  if (t < 128) {
    int qi = t >> 3, dq = (t & 7) * 4;
    *(float4*)&qs[qi][dq] = *(const float4*)&qkvg[(i0 + qi) * 512 + h * 32 + dq];
  }
  {
    int kj = t >> 1, dh = (t & 1) * 16;
    int j = lo + kj;
    if (j >= 0 && j < 768) {
      const float4* sk = (const float4*)&qkvg[j * 512 + 128 + h * 32 + dh];
      const float4* sv = (const float4*)&qkvg[j * 512 + 256 + h * 32 + dh];
#pragma unroll
      for (int m = 0; m < 4; m++) {
        *(float4*)&ks[kj][dh + 4 * m] = sk[m];
        *(float4*)&vs[kj][dh + 4 * m] = sv[m];
      }
    } else {
      float4 zz = {0, 0, 0, 0};
#pragma unroll
      for (int m = 0; m < 4; m++) {
        *(float4*)&ks[kj][dh + 4 * m] = zz;
        *(float4*)&vs[kj][dh + 4 * m] = zz;
      }
    }
  }
  __syncthreads();
  const float scale = 0.17677669529663687f;
  {
    int qi = t & 15, kb = t >> 4;
    float4 qr[8];
#pragma unroll
    for (int m = 0; m < 8; m++) qr[m] = *(float4*)&qs[qi][m * 4];
#pragma unroll
    for (int kk = 0; kk < 8; kk++) {
      int kj = kb * 8 + kk;
      float acc = 0.f;
#pragma unroll
      for (int m = 0; m < 8; m++) {
        float4 kv = *(float4*)&ks[kj][m * 4];
        acc += qr[m].x * kv.x + qr[m].y * kv.y + qr[m].z * kv.z + qr[m].w * kv.w;
      }
      L[qi][kj] += acc * scale;
    }
  }
  __syncthreads();
  int qi = t >> 4, sg = t & 15;
  float mx = -1e30f;
#pragma unroll
  for (int k2 = 0; k2 < 8; k2++) mx = fmaxf(mx, L[qi][sg * 8 + k2]);
#pragma unroll
  for (int o = 1; o < 16; o <<= 1) mx = fmaxf(mx, __shfl_xor(mx, o));
  float sum = 0.f;
#pragma unroll
  for (int k2 = 0; k2 < 8; k2++) {
    int kj = sg * 8 + k2;
    float e = __expf(L[qi][kj] - mx);
    L[qi][kj] = e;
    sum += e;
  }
#pragma unroll
  for (int o = 1; o < 16; o <<= 1) sum += __shfl_xor(sum, o);
  float rden = 1.f / sum;
  __syncthreads();
  {
    int d2 = (t & 15) * 2;
    float a0 = 0.f, a1 = 0.f;
#pragma unroll 8
    for (int kj = 0; kj < 128; kj++) {
      float p = L[qi][kj];
      float2 v = *(float2*)&vs[kj][d2];
      a0 += p * v.x; a1 += p * v.y;
    }
    int i = i0 + qi;
    float2 gr = *(const float2*)&qkvg[i * 512 + 384 + h * 32 + d2];
    float2 o2;
    o2.x = a0 * rden * sigmoidf_(gr.x);
    o2.y = a1 * rden * sigmoidf_(gr.y);
    *(float2*)&og[i * 128 + h * 32 + d2] = o2;
  }
}

// ---------------------------------------------------------------------------
// k_fusedT<MODE>: x += og@Wo; a=LN(x); x += relu(a@Wt1)@Wt2; then
//  MODE 1: qkvg_next = LN_next(x) @ [Wq|Wk|Wv|Wg]
//  MODE 2: qout = relu(x@W_proj), a_out = mean (k_final fused)
// grid 256 (3 rows/block, 1/CU), block 384.  (all GEMM loops: unroll 8)
template <int MODE>
__global__ __launch_bounds__(384) void k_fusedT(
    const float* __restrict__ og, const float* __restrict__ Wo,
    const float* __restrict__ g2, const float* __restrict__ b2,
    const float* __restrict__ Wt1, const float* __restrict__ Wt2,
    float* __restrict__ x,
    const float* __restrict__ lng_n, const float* __restrict__ lnb_n,
    const float* __restrict__ Wq, const float* __restrict__ Wk,
    const float* __restrict__ Wv, const float* __restrict__ Wg,
    float* __restrict__ qkvg, const float* __restrict__ W_proj,
    float* __restrict__ out) {
  int t = threadIdx.x;
  int r0 = blockIdx.x * 3;
  __shared__ float osr[3][128];
  __shared__ float xns[3][128];
  __shared__ float asr[3][128];
  __shared__ float hs[3][512];
  __shared__ float part[4][3][128];
  __shared__ float red[12];
  {
    int rr = t >> 7, c = t & 127;
    osr[rr][c] = og[(r0 + rr) * 128 + c];
    xns[rr][c] = x[(r0 + rr) * 128 + c];
  }
  __syncthreads();
  {
    int c4 = (t & 31) * 4, row = (t >> 5) % 3, q = t / 96;
    int k0 = q * 32;
    float a0 = 0.f, a1 = 0.f, a2 = 0.f, a3 = 0.f;
#pragma unroll 8
    for (int kk = 0; kk < 32; kk++) {
      int k = k0 + kk;
      float4 w = *(const float4*)&Wo[k * 128 + c4];
      float av = osr[row][k];
      a0 += av * w.x; a1 += av * w.y; a2 += av * w.z; a3 += av * w.w;
    }
    *(float4*)&part[q][row][c4] = make_float4(a0, a1, a2, a3);
  }
  __syncthreads();
  {
    int rr = t >> 7, c = t & 127;
    float xv = xns[rr][c] + part[0][rr][c] + part[1][rr][c] + part[2][rr][c] + part[3][rr][c];
    float ps = xv, pq = xv * xv;
#pragma unroll
    for (int o = 1; o < 64; o <<= 1) { ps += __shfl_xor(ps, o); pq += __shfl_xor(pq, o); }
    int wv = t >> 6;
    if ((t & 63) == 0) { red[wv] = ps; red[6 + wv] = pq; }
    __syncthreads();
    float mean = (red[2 * rr] + red[2 * rr + 1]) * (1.f / 128.f);
    float var = (red[6 + 2 * rr] + red[6 + 2 * rr + 1]) * (1.f / 128.f) - mean * mean;
    float rstd = rsqrtf(var + 1e-5f);
    xns[rr][c] = xv;
    asr[rr][c] = (xv - mean) * rstd * g2[c] + b2[c];
  }
  __syncthreads();
  {
    int c4 = (t & 127) * 4, row = t >> 7;
    float a0 = 0.f, a1 = 0.f, a2 = 0.f, a3 = 0.f;
#pragma unroll 8
    for (int k = 0; k < 128; k++) {
      float4 w = *(const float4*)&Wt1[k * 512 + c4];
      float av = asr[row][k];
      a0 += av * w.x; a1 += av * w.y; a2 += av * w.z; a3 += av * w.w;
    }
    *(float4*)&hs[row][c4] = make_float4(fmaxf(a0, 0.f), fmaxf(a1, 0.f),
                                         fmaxf(a2, 0.f), fmaxf(a3, 0.f));
  }
  __syncthreads();
  {
    int c4 = (t & 31) * 4, row = (t >> 5) % 3, q = t / 96;
    int k0 = q * 128;
    float a0 = 0.f, a1 = 0.f, a2 = 0.f, a3 = 0.f;
#pragma unroll 8
    for (int kk = 0; kk < 128; kk++) {
      int k = k0 + kk;
      float4 w = *(const float4*)&Wt2[k * 128 + c4];
      float hv = hs[row][k];
      a0 += hv * w.x; a1 += hv * w.y; a2 += hv * w.z; a3 += hv * w.w;
    }
    *(float4*)&part[q][row][c4] = make_float4(a0, a1, a2, a3);
  }
  __syncthreads();
  {
    int rr = t >> 7, c = t & 127;
    float xf = xns[rr][c] + part[0][rr][c] + part[1][rr][c] +
               part[2][rr][c] + part[3][rr][c];
    x[(r0 + rr) * 128 + c] = xf;
    xns[rr][c] = xf;
  }
  if (MODE == 1) {
    __syncthreads();
    {
      int rr = t >> 7, c = t & 127;
      float xv = xns[rr][c];
      float ps = xv, pq = xv * xv;
#pragma unroll
      for (int o = 1; o < 64; o <<= 1) { ps += __shfl_xor(ps, o); pq += __shfl_xor(pq, o); }
      int wv = t >> 6;
      if ((t & 63) == 0) { red[wv] = ps; red[6 + wv] = pq; }
      __syncthreads();
      float mean = (red[2 * rr] + red[2 * rr + 1]) * (1.f / 128.f);
      float var = (red[6 + 2 * rr] + red[6 + 2 * rr + 1]) * (1.f / 128.f) - mean * mean;
      float rstd = rsqrtf(var + 1e-5f);
      asr[rr][c] = (xv - mean) * rstd * lng_n[c] + lnb_n[c];
    }
    __syncthreads();
    {
      int c4 = (t & 127) * 4, row = t >> 7;
      int mtx = c4 >> 7, lc = c4 & 127;
      const float* Wm = (mtx == 0) ? Wq : (mtx == 1) ? Wk : (mtx == 2) ? Wv : Wg;
      float a0 = 0.f, a1 = 0.f, a2 = 0.f, a3 = 0.f;
#pragma unroll 8
      for (int k = 0; k < 128; k++) {
        float4 w = *(const float4*)&Wm[k * 128 + lc];
        float av = asr[row][k];
        a0 += av * w.x; a1 += av * w.y; a2 += av * w.z; a3 += av * w.w;
      }
      *(float4*)&qkvg[(r0 + row) * 512 + c4] = make_float4(a0, a1, a2, a3);
    }
  }
  if (MODE == 2) {
    __syncthreads();
    int tk = blockIdx.x;
    float a0 = 0.f, a1 = 0.f, a2 = 0.f;
#pragma unroll 8
    for (int k = 0; k < 128; k++) {
      float w = W_proj[k * 384 + t];
      a0 += xns[0][k] * w; a1 += xns[1][k] * w; a2 += xns[2][k] * w;
    }
    a0 = fmaxf(a0, 0.f); a1 = fmaxf(a1, 0.f); a2 = fmaxf(a2, 0.f);
    out[98304 + (tk * 3 + 0) * 384 + t] = a0;
    out[98304 + (tk * 3 + 1) * 384 + t] = a1;
    out[98304 + (tk * 3 + 2) * 384 + t] = a2;
    out[tk * 384 + t] = (a0 + a1 + a2) * (1.f / 3.f);
  }
}

// ---------------------------------------------------------------------------
extern "C" void kernel_launch(void* const* d_in, const int* in_sizes, int n_in,
                              void* d_out, int out_size, void* d_ws, size_t ws_size,
                              hipStream_t stream) {
  const float* ref_pos  = (const float*)d_in[0];
  const int*   uid      = (const int*)d_in[1];
  const float* r        = (const float*)d_in[2];
  const float* s        = (const float*)d_in[3];
  const float* z        = (const float*)d_in[4];
  const float* W_pos    = (const float*)d_in[5];
  const float* Wpo      = (const float*)d_in[6];
  const float* Wisd     = (const float*)d_in[7];
  const float* Wmask    = (const float*)d_in[8];
  const float* Wca      = (const float*)d_in[9];
  const float* Wcb      = (const float*)d_in[10];
  const float* ln_s_g   = (const float*)d_in[11];
  const float* ln_s_b   = (const float*)d_in[12];
  const float* W_single = (const float*)d_in[13];
  const float* ln_z_g   = (const float*)d_in[14];
  const float* ln_z_b   = (const float*)d_in[15];
  const float* W_pair   = (const float*)d_in[16];
  const float* W_noisy  = (const float*)d_in[17];
  const float* W_mlp1   = (const float*)d_in[18];
  const float* W_mlp2   = (const float*)d_in[19];
  const float* W_mlp3   = (const float*)d_in[20];
  const float* at_ln_g  = (const float*)d_in[21];
  const float* at_ln_b  = (const float*)d_in[22];
  const float* at_Wq    = (const float*)d_in[23];
  const float* at_Wk    = (const float*)d_in[24];
  const float* at_Wv    = (const float*)d_in[25];
  const float* at_Wg    = (const float*)d_in[26];
  const float* at_lnp_g = (const float*)d_in[27];
  const float* at_lnp_b = (const float*)d_in[28];
  const float* at_Wb    = (const float*)d_in[29];
  const float* at_Wo    = (const float*)d_in[30];
  const float* at_ln2_g = (const float*)d_in[31];
  const float* at_ln2_b = (const float*)d_in[32];
  const float* at_Wt1   = (const float*)d_in[33];
  const float* at_Wt2   = (const float*)d_in[34];
  const float* W_proj   = (const float*)d_in[35];
  float* out = (float*)d_out;
  float* W = (float*)d_ws;
  float* x     = W;                 //   98304
  float* ca    = W + 98304;         //   12288
  float* cb    = W + 110592;        //   12288
  float* zp    = W + 122880;        // 1048576
  float* biasA = W + 1171456;       // 1179648
  float* qkvg  = W + 2351104;       //  393216
  float* og    = W + 2744320;       //   98304

  k_front<<<1280, 256, 0, stream>>>(z, ln_z_g, ln_z_b, W_pair, zp,
                                    s, ln_s_g, ln_s_b, W_single, ref_pos, r,
                                    W_pos, W_noisy, Wca, Wcb,
                                    out + 393216, x, ca, cb);
  k_pairq<<<2688, 256, 0, stream>>>(ref_pos, uid, Wpo, Wisd, Wmask, W_mlp1, W_mlp2,
                                    W_mlp3, zp, ca, cb, at_lnp_g, at_lnp_b, at_Wb,
                                    out + 491520, biasA,
                                    x, at_ln_g, at_ln_b, at_Wq, at_Wk, at_Wv, at_Wg,
                                    qkvg);
  // layer 0
  k_attn2<<<192, 256, 0, stream>>>(qkvg, biasA, og);
  k_fusedT<1><<<256, 384, 0, stream>>>(og, at_Wo, at_ln2_g, at_ln2_b, at_Wt1, at_Wt2, x,
                                       at_ln_g + 128, at_ln_b + 128,
                                       at_Wq + 16384, at_Wk + 16384,
                                       at_Wv + 16384, at_Wg + 16384, qkvg,
                                       nullptr, nullptr);
  // layer 1
  k_attn2<<<192, 256, 0, stream>>>(qkvg, biasA + 393216, og);
  k_fusedT<1><<<256, 384, 0, stream>>>(og, at_Wo + 16384, at_ln2_g + 128, at_ln2_b + 128,
                                       at_Wt1 + 65536, at_Wt2 + 65536, x,
                                       at_ln_g + 256, at_ln_b + 256,
                                       at_Wq + 32768, at_Wk + 32768,
                                       at_Wv + 32768, at_Wg + 32768, qkvg,
                                       nullptr, nullptr);
  // layer 2
  k_attn2<<<192, 256, 0, stream>>>(qkvg, biasA + 786432, og);
  k_fusedT<2><<<256, 384, 0, stream>>>(og, at_Wo + 32768, at_ln2_g + 256, at_ln2_b + 256,
                                       at_Wt1 + 131072, at_Wt2 + 131072, x,
                                       nullptr, nullptr, nullptr, nullptr,
                                       nullptr, nullptr, nullptr, W_proj, out);
}

// Round 17
// 143.267 us; speedup vs baseline: 1.4523x; 1.0145x over previous
//
#include <hip/hip_runtime.h>
#include <math.h>

// N=768 atoms, T=256 tokens, CA=128, CP=16, CZ=128, CS=384, CT=384, H=4, DH=32
// d_out: a_out[256*384]@0, qout[768*384]@98304, c[768*128]@393216, pair[768*768*16]@491520

__device__ __forceinline__ float sigmoidf_(float v) { return 1.f / (1.f + __expf(-v)); }

typedef __attribute__((ext_vector_type(4))) short s16x4;
typedef __attribute__((ext_vector_type(8))) short s16x8;
typedef __attribute__((ext_vector_type(4))) float f32x4;

__device__ __forceinline__ unsigned bfpack(float a, float b) {
  return (__float_as_uint(a) >> 16) | (__float_as_uint(b) & 0xFFFF0000u);
}
__device__ __forceinline__ short bf1(float a) { return (short)(__float_as_uint(a) >> 16); }

// ---------------------------------------------------------------------------
// k_front: bid<1024 -> zp via MFMA (64 z-rows/block) ; bid>=1024 -> tokatoms
// grid 1280, block 256.
__global__ __launch_bounds__(256) void k_front(
    const float* __restrict__ z, const float* __restrict__ zg,
    const float* __restrict__ zlb, const float* __restrict__ W_pair,
    float* __restrict__ zp,
    const float* __restrict__ s, const float* __restrict__ g,
    const float* __restrict__ b, const float* __restrict__ W_single,
    const float* __restrict__ ref_pos, const float* __restrict__ r,
    const float* __restrict__ W_pos, const float* __restrict__ W_noisy,
    const float* __restrict__ Wca, const float* __restrict__ Wcb,
    float* __restrict__ c_out, float* __restrict__ x,
    float* __restrict__ ca, float* __restrict__ cb) {
  __shared__ __align__(128) float sm[5392];
  int t = threadIdx.x;
  int bid = blockIdx.x;
  if (bid < 1024) {
    float* bcp = sm + 5120;
    float* Bc = sm + 5376;
    {
      int ch = t & 15, kseg = t >> 4;
      float a = 0.f;
#pragma unroll
      for (int e = 0; e < 8; e++) {
        int k = kseg * 8 + e;
        a += zlb[k] * W_pair[k * 16 + ch];
      }
      bcp[kseg * 16 + ch] = a;
    }
    __syncthreads();
    if (t < 16) {
      float a = 0.f;
#pragma unroll
      for (int kseg = 0; kseg < 16; kseg++) a += bcp[kseg * 16 + t];
      Bc[t] = a;
    }
    __syncthreads();
    int w = t >> 6, l = t & 63;
    int kb = l & 15, rg = l >> 4;
    int row0 = bid * 64 + w * 16;
    char* stgw = (char*)(sm + w * 1280);
    float4 za[4], zb[4];
    float m_[4], rs_[4];
#pragma unroll
    for (int rr = 0; rr < 4; rr++) {
      long base = (long)(row0 + rg * 4 + rr) * 128 + kb * 8;
      za[rr] = *(const float4*)&z[base];
      zb[rr] = *(const float4*)&z[base + 4];
      float ps = za[rr].x + za[rr].y + za[rr].z + za[rr].w +
                 zb[rr].x + zb[rr].y + zb[rr].z + zb[rr].w;
      float pq = za[rr].x * za[rr].x + za[rr].y * za[rr].y + za[rr].z * za[rr].z +
                 za[rr].w * za[rr].w + zb[rr].x * zb[rr].x + zb[rr].y * zb[rr].y +
                 zb[rr].z * zb[rr].z + zb[rr].w * zb[rr].w;
#pragma unroll
      for (int o = 1; o < 16; o <<= 1) { ps += __shfl_xor(ps, o); pq += __shfl_xor(pq, o); }
      m_[rr] = ps * (1.f / 128.f);
      rs_[rr] = rsqrtf(pq * (1.f / 128.f) - m_[rr] * m_[rr] + 1e-5f);
    }
    {
      int kc = kb >> 1;
      int cbase = (kb & 1) * 8;
#pragma unroll
      for (int e = 0; e < 8; e++) {
        float a0 = ((e < 4 ? (&za[0].x)[e] : (&zb[0].x)[e - 4]) - m_[0]) * rs_[0];
        float a1 = ((e < 4 ? (&za[1].x)[e] : (&zb[1].x)[e - 4]) - m_[1]) * rs_[1];
        float a2 = ((e < 4 ? (&za[2].x)[e] : (&zb[2].x)[e - 4]) - m_[2]) * rs_[2];
        float a3 = ((e < 4 ? (&za[3].x)[e] : (&zb[3].x)[e - 4]) - m_[3]) * rs_[3];
        char* wp = stgw + kc * 640 + (cbase + e) * 32 + rg * 8;
        *(uint2*)wp = make_uint2(bfpack(a0, a1), bfpack(a2, a3));
      }
    }
    int c = l & 15;
    s16x8 bw[8];
#pragma unroll
    for (int kc = 0; kc < 8; kc++) {
      short e0, e1, e2, e3;
      {
        int kk = kc * 16 + 4 * rg;
        e0 = bf1(zg[kk] * W_pair[kk * 16 + c]);
        e1 = bf1(zg[kk + 1] * W_pair[(kk + 1) * 16 + c]);
        e2 = bf1(zg[kk + 2] * W_pair[(kk + 2) * 16 + c]);
        e3 = bf1(zg[kk + 3] * W_pair[(kk + 3) * 16 + c]);
      }
      bw[kc] = s16x8{e0, e1, e2, e3, (short)0, (short)0, (short)0, (short)0};
    }
    unsigned sbase = (unsigned)(uintptr_t)stgw;
    f32x4 acc = {0.f, 0.f, 0.f, 0.f};
#pragma unroll
    for (int kc = 0; kc < 8; kc++) {
      unsigned ra = sbase + (unsigned)(kc * 640 + c * 8 + rg * 128);
      s16x4 tr;
      asm volatile("s_waitcnt lgkmcnt(0)\n\tds_read_b64_tr_b16 %0, %1\n\ts_waitcnt lgkmcnt(0)"
                   : "=v"(tr) : "v"(ra) : "memory");
      s16x8 a8 = {tr[0], tr[1], tr[2], tr[3], (short)0, (short)0, (short)0, (short)0};
      acc = __builtin_amdgcn_mfma_f32_16x16x32_bf16(a8, bw[kc], acc, 0, 0, 0);
    }
    float bc = Bc[c];
#pragma unroll
    for (int rr = 0; rr < 4; rr++) {
      int row = row0 + rg * 4 + rr;
      zp[(long)row * 16 + c] = acc[rr] + bc;
    }
  } else {
    int tok = bid - 1024;
    float* sln = sm;
    float* ws = sm + 384;
    float* red = sm + 4480;
    float* rc = sm + 4488;
    float v0 = 0.f, v1 = 0.f, v2 = 0.f;
    if (t < 128) {
      v0 = s[tok * 384 + t]; v1 = s[tok * 384 + 128 + t]; v2 = s[tok * 384 + 256 + t];
      float ps = v0 + v1 + v2, pq = v0 * v0 + v1 * v1 + v2 * v2;
#pragma unroll
      for (int o = 1; o < 64; o <<= 1) { ps += __shfl_xor(ps, o); pq += __shfl_xor(pq, o); }
      if ((t & 63) == 0) { red[t >> 6] = ps; red[2 + (t >> 6)] = pq; }
    }
    __syncthreads();
    float ctv = 0.f;
    if (t < 128) {
      float mean = (red[0] + red[1]) * (1.f / 384.f);
      float var = (red[2] + red[3]) * (1.f / 384.f) - mean * mean;
      float rstd = rsqrtf(var + 1e-5f);
      sln[t] = (v0 - mean) * rstd * g[t] + b[t];
      sln[128 + t] = (v1 - mean) * rstd * g[128 + t] + b[128 + t];
      sln[256 + t] = (v2 - mean) * rstd * g[256 + t] + b[256 + t];
    }
    for (int c0 = 0; c0 < 384; c0 += 32) {
      __syncthreads();
#pragma unroll
      for (int m = 0; m < 4; m++) {
        int idx = (t + 256 * m) * 4;
        *(float4*)&ws[idx] = *(const float4*)&W_single[c0 * 128 + idx];
      }
      __syncthreads();
      if (t < 128) {
#pragma unroll 8
        for (int kk = 0; kk < 32; kk++) ctv += sln[c0 + kk] * ws[kk * 128 + t];
      }
    }
    float wp0 = 0.f, wp1 = 0.f, wp2 = 0.f, wn0 = 0.f, wn1 = 0.f, wn2 = 0.f;
    if (t < 128) {
      wp0 = W_pos[t]; wp1 = W_pos[128 + t]; wp2 = W_pos[256 + t];
      wn0 = W_noisy[t]; wn1 = W_noisy[128 + t]; wn2 = W_noisy[256 + t];
    }
#pragma unroll
    for (int a = 0; a < 3; a++) {
      int i = tok + 256 * a;
      float cc = 0.f;
      if (t < 128) {
        float p0 = ref_pos[i * 3], p1 = ref_pos[i * 3 + 1], p2 = ref_pos[i * 3 + 2];
        float r0 = r[i * 3], r1 = r[i * 3 + 1], r2 = r[i * 3 + 2];
        float c0 = p0 * wp0 + p1 * wp1 + p2 * wp2;
        x[i * 128 + t] = c0 + r0 * wn0 + r1 * wn1 + r2 * wn2;
        cc = c0 + ctv;
        c_out[i * 128 + t] = cc;
      }
      __syncthreads();
      if (t < 128) rc[t] = fmaxf(cc, 0.f);
      __syncthreads();
      if (t < 128) {
        int out_id = t >> 2, q = t & 3;
        const float* Wm = (out_id < 16) ? Wca : Wcb;
        int ch = out_id & 15;
        float acc = 0.f;
#pragma unroll
        for (int kk = 0; kk < 32; kk++) { int k = q * 32 + kk; acc += rc[k] * Wm[k * 16 + ch]; }
        acc += __shfl_xor(acc, 1);
        acc += __shfl_xor(acc, 2);
        if (q == 0) { if (out_id < 16) ca[i * 16 + ch] = acc; else cb[i * 16 + ch] = acc; }
      }
    }
  }
}

// ---------------------------------------------------------------------------
// k_pairq: bid<2304 -> pairM ; bid>=2304 -> qkvg layer-0 (direct weights)
// grid 2688, block 256
__global__ __launch_bounds__(256) void k_pairq(
    const float* __restrict__ ref_pos, const int* __restrict__ uid,
    const float* __restrict__ Wpo, const float* __restrict__ Wisd,
    const float* __restrict__ Wmask, const float* __restrict__ W1,
    const float* __restrict__ W2, const float* __restrict__ W3,
    const float* __restrict__ zp, const float* __restrict__ ca,
    const float* __restrict__ cb, const float* __restrict__ lnp_g,
    const float* __restrict__ lnp_b, const float* __restrict__ Wb,
    float* __restrict__ pair_out, float* __restrict__ biasA,
    const float* __restrict__ x, const float* __restrict__ lng,
    const float* __restrict__ lnb, const float* __restrict__ Wq,
    const float* __restrict__ Wk, const float* __restrict__ Wv,
    const float* __restrict__ Wg, float* __restrict__ qkvg) {
  __shared__ float jsx[256], jsy[256], jsz[256];
  __shared__ int jsu[256];
  __shared__ __align__(128) short stg[4][1280];
  __shared__ __align__(16) float pfs[4][1056];
  __shared__ float wgb[192];
  __shared__ float kbs[12];
  int t = threadIdx.x;
  int bid = blockIdx.x;
  if (bid >= 2304) {
    int r0 = (bid - 2304) * 2;
    float* asr_ = jsx;
    float* red_ = jsy;
    int row = t >> 7, c = t & 127;
    float xv = x[(r0 + row) * 128 + c];
    {
      float ps = xv, pq = xv * xv;
#pragma unroll
      for (int o = 1; o < 64; o <<= 1) { ps += __shfl_xor(ps, o); pq += __shfl_xor(pq, o); }
      int wv = t >> 6;
      if ((t & 63) == 0) { red_[wv] = ps; red_[4 + wv] = pq; }
      __syncthreads();
      float mean = (red_[2 * row] + red_[2 * row + 1]) * (1.f / 128.f);
      float var = (red_[4 + 2 * row] + red_[4 + 2 * row + 1]) * (1.f / 128.f) - mean * mean;
      float rstd = rsqrtf(var + 1e-5f);
      asr_[row * 128 + c] = (xv - mean) * rstd * lng[c] + lnb[c];
    }
    __syncthreads();
    {
      int c4 = (t & 127) * 4, row2 = t >> 7;
      int mtx = c4 >> 7, lc = c4 & 127;
      const float* Wm = (mtx == 0) ? Wq : (mtx == 1) ? Wk : (mtx == 2) ? Wv : Wg;
      float a0 = 0.f, a1 = 0.f, a2 = 0.f, a3 = 0.f;
#pragma unroll 8
      for (int k = 0; k < 128; k++) {
        float4 w = *(const float4*)&Wm[k * 128 + lc];
        float av = asr_[row2 * 128 + k];
        a0 += av * w.x; a1 += av * w.y; a2 += av * w.z; a3 += av * w.w;
      }
      *(float4*)&qkvg[(r0 + row2) * 512 + c4] = make_float4(a0, a1, a2, a3);
    }
    return;
  }
  int i = bid / 3, jb = bid % 3;
  int jg = jb * 256 + t;
  jsx[t] = ref_pos[jg * 3];
  jsy[t] = ref_pos[jg * 3 + 1];
  jsz[t] = ref_pos[jg * 3 + 2];
  jsu[t] = uid[jg];
  if (t >= 64) {
    int e = t - 64;
    if (e < 192) {
      int bq = e >> 6, k = (e >> 2) & 15, h = e & 3;
      wgb[e] = lnp_g[bq * 16 + k] * Wb[bq * 64 + k * 4 + h];
    }
  }
  if (t >= 48 && t < 60) {
    int e = t - 48, bq = e >> 2, h = e & 3;
    float a = 0.f;
#pragma unroll
    for (int cc = 0; cc < 16; cc++) a += lnp_b[bq * 16 + cc] * Wb[bq * 64 + cc * 4 + h];
    kbs[e] = a;
  }
  int w = t >> 6, l = t & 63;
  int c = l & 15, gr = l >> 4;
  float pix = ref_pos[i * 3], piy = ref_pos[i * 3 + 1], piz = ref_pos[i * 3 + 2];
  int ui = uid[i];
  float w0c = Wpo[c], w1c = Wpo[16 + c], w2c = Wpo[32 + c];
  float wic = Wisd[c], wmc = Wmask[c], cac = ca[i * 16 + c];
  s16x8 bw0 = {bf1(W1[(4 * gr + 0) * 16 + c]), bf1(W1[(4 * gr + 1) * 16 + c]),
               bf1(W1[(4 * gr + 2) * 16 + c]), bf1(W1[(4 * gr + 3) * 16 + c]),
               (short)0, (short)0, (short)0, (short)0};
  s16x8 bw1 = {bf1(W2[(4 * gr + 0) * 16 + c]), bf1(W2[(4 * gr + 1) * 16 + c]),
               bf1(W2[(4 * gr + 2) * 16 + c]), bf1(W2[(4 * gr + 3) * 16 + c]),
               (short)0, (short)0, (short)0, (short)0};
  s16x8 bw2 = {bf1(W3[(4 * gr + 0) * 16 + c]), bf1(W3[(4 * gr + 1) * 16 + c]),
               bf1(W3[(4 * gr + 2) * 16 + c]), bf1(W3[(4 * gr + 3) * 16 + c]),
               (short)0, (short)0, (short)0, (short)0};
  __syncthreads();
  char* sb = (char*)&stg[w][0];
  unsigned sbase = (unsigned)(uintptr_t)sb;
  f32x4 z4 = {0.f, 0.f, 0.f, 0.f};
#pragma unroll
  for (int g = 0; g < 4; g++) {
    float p0_, p1_, p2_, p3_;
    {
      int jl0 = w * 64 + g * 16 + 4 * gr;
#pragma unroll
      for (int r = 0; r < 4; r++) {
        int jloc = jl0 + r;
        int j = jb * 256 + jloc;
        float d0 = pix - jsx[jloc], d1 = piy - jsy[jloc], d2 = piz - jsz[jloc];
        float mk = (ui == jsu[jloc]) ? 1.f : 0.f;
        float inv = 1.f / (1.f + d0 * d0 + d1 * d1 + d2 * d2);
        float zv = zp[((long)((i & 255) << 8) + jloc) * 16 + c];
        float cbv = cb[j * 16 + c];
        float pv = mk * (d0 * w0c + d1 * w1c + d2 * w2c + inv * wic + wmc) + zv + cbv + cac;
        if (r == 0) p0_ = pv; else if (r == 1) p1_ = pv; else if (r == 2) p2_ = pv; else p3_ = pv;
      }
    }
    char* wp = sb + g * 640 + c * 32 + gr * 8;
    unsigned ra = sbase + (unsigned)(g * 640 + c * 8 + gr * 128);
    *(uint2*)wp = make_uint2(bfpack(fmaxf(p0_, 0.f), fmaxf(p1_, 0.f)),
                             bfpack(fmaxf(p2_, 0.f), fmaxf(p3_, 0.f)));
    s16x4 tr0;
    asm volatile("s_waitcnt lgkmcnt(0)\n\tds_read_b64_tr_b16 %0, %1\n\ts_waitcnt lgkmcnt(0)"
                 : "=v"(tr0) : "v"(ra) : "memory");
    s16x8 a8 = {tr0[0], tr0[1], tr0[2], tr0[3], (short)0, (short)0, (short)0, (short)0};
    f32x4 h1 = __builtin_amdgcn_mfma_f32_16x16x32_bf16(a8, bw0, z4, 0, 0, 0);
    *(uint2*)wp = make_uint2(bfpack(fmaxf(h1[0], 0.f), fmaxf(h1[1], 0.f)),
                             bfpack(fmaxf(h1[2], 0.f), fmaxf(h1[3], 0.f)));
    s16x4 tr1;
    asm volatile("s_waitcnt lgkmcnt(0)\n\tds_read_b64_tr_b16 %0, %1\n\ts_waitcnt lgkmcnt(0)"
                 : "=v"(tr1) : "v"(ra) : "memory");
    s16x8 a8b = {tr1[0], tr1[1], tr1[2], tr1[3], (short)0, (short)0, (short)0, (short)0};
    f32x4 h2 = __builtin_amdgcn_mfma_f32_16x16x32_bf16(a8b, bw1, z4, 0, 0, 0);
    *(uint2*)wp = make_uint2(bfpack(fmaxf(h2[0], 0.f), fmaxf(h2[1], 0.f)),
                             bfpack(fmaxf(h2[2], 0.f), fmaxf(h2[3], 0.f)));
    s16x4 tr2;
    asm volatile("s_waitcnt lgkmcnt(0)\n\tds_read_b64_tr_b16 %0, %1\n\ts_waitcnt lgkmcnt(0)"
                 : "=v"(tr2) : "v"(ra) : "memory");
    s16x8 a8c = {tr2[0], tr2[1], tr2[2], tr2[3], (short)0, (short)0, (short)0, (short)0};
    f32x4 h3 = __builtin_amdgcn_mfma_f32_16x16x32_bf16(a8c, bw2, z4, 0, 0, 0);
    float f0 = p0_ + h3[0], f1 = p1_ + h3[1], f2 = p2_ + h3[2], f3 = p3_ + h3[3];
    {
      int jl0 = w * 64 + g * 16 + 4 * gr;
      long pb = ((long)i * 768 + (long)(jb * 256 + jl0)) * 16 + c;
      pair_out[pb] = f0;
      pair_out[pb + 16] = f1;
      pair_out[pb + 32] = f2;
      pair_out[pb + 48] = f3;
    }
    *(float4*)&pfs[w][g * 264 + c * 16 + 4 * gr] = make_float4(f0, f1, f2, f3);
  }
  asm volatile("s_waitcnt lgkmcnt(0)" ::: "memory");
  int qb = i >> 5;
  int j = jb * 256 + t;
  unsigned jw = (unsigned)(j - (qb * 32 - 48));
  if (jw < 128u) {
    int gt = (t >> 4) & 3, jr = t & 15;
    float v[16];
#pragma unroll
    for (int cc = 0; cc < 16; cc++) v[cc] = pfs[w][gt * 264 + cc * 16 + jr];
    float m = 0.f;
#pragma unroll
    for (int cc = 0; cc < 16; cc++) m += v[cc];
    m *= (1.f / 16.f);
    float vv = 0.f;
#pragma unroll
    for (int cc = 0; cc < 16; cc++) { float d = v[cc] - m; vv += d * d; }
    float rs = rsqrtf(vv * (1.f / 16.f) + 1e-5f);
    float nrm[16];
#pragma unroll
    for (int cc = 0; cc < 16; cc++) nrm[cc] = (v[cc] - m) * rs;
    int qi = i & 31;
#pragma unroll
    for (int bq = 0; bq < 3; bq++) {
      float o0 = kbs[bq * 4 + 0], o1 = kbs[bq * 4 + 1];
      float o2 = kbs[bq * 4 + 2], o3 = kbs[bq * 4 + 3];
#pragma unroll
      for (int k = 0; k < 16; k++) {
        float nv = nrm[k];
        float4 wv = *(float4*)&wgb[bq * 64 + k * 4];
        o0 += nv * wv.x; o1 += nv * wv.y; o2 += nv * wv.z; o3 += nv * wv.w;
      }
      long base = (long)(bq * 96 + qb * 4) * 4096 + (long)qi * 128 + jw;
      biasA[base] = o0;
      biasA[base + 4096] = o1;
      biasA[base + 2 * 4096] = o2;
      biasA[base + 3 * 4096] = o3;
    }
  }
}

// ---------------------------------------------------------------------------
// k_attn2: windowed attention, 16-row q-tiles.  grid 192 (qt*4+h), block 256
__global__ __launch_bounds__(256) void k_attn2(
    const float* __restrict__ qkvg, const float* __restrict__ biasb,
    float* __restrict__ og) {
  int qt = blockIdx.x >> 2, h = blockIdx.x & 3, t = threadIdx.x;
  int i0 = qt * 16;
  int qb32 = qt >> 1;
  int lo = qb32 * 32 - 48;
  int qoff = (qt & 1) * 16;
  __shared__ float qs[16][36];
  __shared__ float ks[128][36];
  __shared__ float vs[128][36];
  __shared__ float L[16][132];
  {
    int e = t * 8;
    int qi = e >> 7, k8 = e & 127;
    const float* bb = &biasb[(long)(qb32 * 4 + h) * 4096 + (long)(qoff + qi) * 128];
#pragma unroll
    for (int m = 0; m < 2; m++) {
      int k4 = k8 + m * 4;
      int j4 = lo + k4;
      float4 bv;
      if (j4 >= 0 && j4 <= 764) bv = *(const float4*)&bb[k4];
      else bv = make_float4(-1e30f, -1e30f, -1e30f, -1e30f);
      *(float4*)&L[qi][k4] = bv;
    }
  }
  if (t < 128) {
    int qi = t >> 3, dq = (t & 7) * 4;
    *(float4*)&qs[qi][dq] = *(const float4*)&qkvg[(i0 + qi) * 512 + h * 32 + dq];
  }
  {
    int kj = t >> 1, dh = (t & 1) * 16;
    int j = lo + kj;
    if (j >= 0 && j < 768) {
      const float4* sk = (const float4*)&qkvg[j * 512 + 128 + h * 32 + dh];
      const float4* sv = (const float4*)&qkvg[j * 512 + 256 + h * 32 + dh];
#pragma unroll
      for (int m = 0; m < 4; m++) {
        *(float4*)&ks[kj][dh + 4 * m] = sk[m];
        *(float4*)&vs[kj][dh + 4 * m] = sv[m];
      }
    } else {
      float4 zz = {0, 0, 0, 0};
#pragma unroll
      for (int m = 0; m < 4; m++) {
        *(float4*)&ks[kj][dh + 4 * m] = zz;
        *(float4*)&vs[kj][dh + 4 * m] = zz;
      }
    }
  }
  __syncthreads();
  const float scale = 0.17677669529663687f;
  {
    int qi = t & 15, kb = t >> 4;
    float4 qr[8];
#pragma unroll
    for (int m = 0; m < 8; m++) qr[m] = *(float4*)&qs[qi][m * 4];
#pragma unroll
    for (int kk = 0; kk < 8; kk++) {
      int kj = kb * 8 + kk;
      float acc = 0.f;
#pragma unroll
      for (int m = 0; m < 8; m++) {
        float4 kv = *(float4*)&ks[kj][m * 4];
        acc += qr[m].x * kv.x + qr[m].y * kv.y + qr[m].z * kv.z + qr[m].w * kv.w;
      }
      L[qi][kj] += acc * scale;
    }
  }
  __syncthreads();
  int qi = t >> 4, sg = t & 15;
  float mx = -1e30f;
#pragma unroll
  for (int k2 = 0; k2 < 8; k2++) mx = fmaxf(mx, L[qi][sg * 8 + k2]);
#pragma unroll
  for (int o = 1; o < 16; o <<= 1) mx = fmaxf(mx, __shfl_xor(mx, o));
  float sum = 0.f;
#pragma unroll
  for (int k2 = 0; k2 < 8; k2++) {
    int kj = sg * 8 + k2;
    float e = __expf(L[qi][kj] - mx);
    L[qi][kj] = e;
    sum += e;
  }
#pragma unroll
  for (int o = 1; o < 16; o <<= 1) sum += __shfl_xor(sum, o);
  float rden = 1.f / sum;
  __syncthreads();
  {
    int d2 = (t & 15) * 2;
    float a0 = 0.f, a1 = 0.f;
#pragma unroll 8
    for (int kj = 0; kj < 128; kj++) {
      float p = L[qi][kj];
      float2 v = *(float2*)&vs[kj][d2];
      a0 += p * v.x; a1 += p * v.y;
    }
    int i = i0 + qi;
    float2 gr = *(const float2*)&qkvg[i * 512 + 384 + h * 32 + d2];
    float2 o2;
    o2.x = a0 * rden * sigmoidf_(gr.x);
    o2.y = a1 * rden * sigmoidf_(gr.y);
    *(float2*)&og[i * 128 + h * 32 + d2] = o2;
  }
}

// ---------------------------------------------------------------------------
// k_fusedT<MODE>: x += og@Wo; a=LN(x); x += relu(a@Wt1)@Wt2; then
//  MODE 1: qkvg_next = LN_next(x) @ [Wq|Wk|Wv|Wg]
//  MODE 2: qout = relu(x@W_proj), a_out = mean
// grid 256 (3 rows/block, 1/CU), block 512 (8 waves).  All threads accumulate
// all 3 rows per weight load (no redundant weight traffic); k-split partials
// in LDS.
template <int MODE>
__global__ __launch_bounds__(512) void k_fusedT(
    const float* __restrict__ og, const float* __restrict__ Wo,
    const float* __restrict__ g2, const float* __restrict__ b2,
    const float* __restrict__ Wt1, const float* __restrict__ Wt2,
    float* __restrict__ x,
    const float* __restrict__ lng_n, const float* __restrict__ lnb_n,
    const float* __restrict__ Wq, const float* __restrict__ Wk,
    const float* __restrict__ Wv, const float* __restrict__ Wg,
    float* __restrict__ qkvg, const float* __restrict__ W_proj,
    float* __restrict__ out) {
  int t = threadIdx.x;
  int r0 = blockIdx.x * 3;
  __shared__ float osr[3][128];
  __shared__ float xns[3][128];
  __shared__ float asr[3][128];
  __shared__ float hs[3][512];
  __shared__ float part[4][3][128];
  __shared__ float part2[4][3][512];
  __shared__ float red[12];
  if (t < 384) {
    int rr = t >> 7, c = t & 127;
    osr[rr][c] = og[(r0 + rr) * 128 + c];
    xns[rr][c] = x[(r0 + rr) * 128 + c];
  }
  __syncthreads();
  // ---- GEMM1 (t<384: 4 cols x 32 k x 1 row) ----
  if (t < 384) {
    int c4 = (t & 31) * 4, row = (t >> 5) % 3, q = t / 96;
    int k0 = q * 32;
    float a0 = 0.f, a1 = 0.f, a2 = 0.f, a3 = 0.f;
#pragma unroll 8
    for (int kk = 0; kk < 32; kk++) {
      int k = k0 + kk;
      float4 w = *(const float4*)&Wo[k * 128 + c4];
      float av = osr[row][k];
      a0 += av * w.x; a1 += av * w.y; a2 += av * w.z; a3 += av * w.w;
    }
    *(float4*)&part[q][row][c4] = make_float4(a0, a1, a2, a3);
  }
  __syncthreads();
  // ---- combine + LN (t<384) ----
  if (t < 384) {
    int rr = t >> 7, c = t & 127;
    float xv = xns[rr][c] + part[0][rr][c] + part[1][rr][c] + part[2][rr][c] + part[3][rr][c];
    float ps = xv, pq = xv * xv;
#pragma unroll
    for (int o = 1; o < 64; o <<= 1) { ps += __shfl_xor(ps, o); pq += __shfl_xor(pq, o); }
    int wv = t >> 6;
    if ((t & 63) == 0) { red[wv] = ps; red[6 + wv] = pq; }
  }
  __syncthreads();
  if (t < 384) {
    int rr = t >> 7, c = t & 127;
    float xv = xns[rr][c] + part[0][rr][c] + part[1][rr][c] + part[2][rr][c] + part[3][rr][c];
    float mean = (red[2 * rr] + red[2 * rr + 1]) * (1.f / 128.f);
    float var = (red[6 + 2 * rr] + red[6 + 2 * rr + 1]) * (1.f / 128.f) - mean * mean;
    float rstd = rsqrtf(var + 1e-5f);
    xns[rr][c] = xv;
    asr[rr][c] = (xv - mean) * rstd * g2[c] + b2[c];
  }
  __syncthreads();
  // ---- GEMM2 (all 512 threads, all 3 rows): cg = t&127 (4 cols), ks = t>>7 (32 k) ----
  {
    int cg4 = (t & 127) * 4, ks = t >> 7;
    int k0 = ks * 32;
    float a00 = 0.f, a01 = 0.f, a02 = 0.f, a03 = 0.f;
    float a10 = 0.f, a11 = 0.f, a12 = 0.f, a13 = 0.f;
    float a20 = 0.f, a21 = 0.f, a22 = 0.f, a23 = 0.f;
#pragma unroll 8
    for (int kk = 0; kk < 32; kk++) {
      int k = k0 + kk;
      float4 w = *(const float4*)&Wt1[k * 512 + cg4];
      float v0 = asr[0][k], v1 = asr[1][k], v2 = asr[2][k];
      a00 += v0 * w.x; a01 += v0 * w.y; a02 += v0 * w.z; a03 += v0 * w.w;
      a10 += v1 * w.x; a11 += v1 * w.y; a12 += v1 * w.z; a13 += v1 * w.w;
      a20 += v2 * w.x; a21 += v2 * w.y; a22 += v2 * w.z; a23 += v2 * w.w;
    }
    *(float4*)&part2[ks][0][cg4] = make_float4(a00, a01, a02, a03);
    *(float4*)&part2[ks][1][cg4] = make_float4(a10, a11, a12, a13);
    *(float4*)&part2[ks][2][cg4] = make_float4(a20, a21, a22, a23);
  }
  __syncthreads();
  // combine -> hs (thread t covers col t)
  {
#pragma unroll
    for (int row = 0; row < 3; row++) {
      float v = part2[0][row][t] + part2[1][row][t] + part2[2][row][t] + part2[3][row][t];
      hs[row][t] = fmaxf(v, 0.f);
    }
  }
  __syncthreads();
  // ---- GEMM3 (all 512 threads): cg = t&31 (4 cols), ks = t>>5 (16 splits x 32 k) ----
  {
    int cg4 = (t & 31) * 4, ks = t >> 5;
    int k0 = ks * 32;
    float a00 = 0.f, a01 = 0.f, a02 = 0.f, a03 = 0.f;
    float a10 = 0.f, a11 = 0.f, a12 = 0.f, a13 = 0.f;
    float a20 = 0.f, a21 = 0.f, a22 = 0.f, a23 = 0.f;
#pragma unroll 8
    for (int kk = 0; kk < 32; kk++) {
      int k = k0 + kk;
      float4 w = *(const float4*)&Wt2[k * 128 + cg4];
      float v0 = hs[0][k], v1 = hs[1][k], v2 = hs[2][k];
      a00 += v0 * w.x; a01 += v0 * w.y; a02 += v0 * w.z; a03 += v0 * w.w;
      a10 += v1 * w.x; a11 += v1 * w.y; a12 += v1 * w.z; a13 += v1 * w.w;
      a20 += v2 * w.x; a21 += v2 * w.y; a22 += v2 * w.z; a23 += v2 * w.w;
    }
    // part2 reused as [16][3][128]
    float* p3 = &part2[0][0][0];
    *(float4*)&p3[(ks * 3 + 0) * 128 + cg4] = make_float4(a00, a01, a02, a03);
    *(float4*)&p3[(ks * 3 + 1) * 128 + cg4] = make_float4(a10, a11, a12, a13);
    *(float4*)&p3[(ks * 3 + 2) * 128 + cg4] = make_float4(a20, a21, a22, a23);
  }
  __syncthreads();
  // ---- combine + final x (t<384) ----
  if (t < 384) {
    int rr = t >> 7, c = t & 127;
    const float* p3 = &part2[0][0][0];
    float acc = 0.f;
#pragma unroll
    for (int ks = 0; ks < 16; ks++) acc += p3[(ks * 3 + rr) * 128 + c];
    float xf = xns[rr][c] + acc;
    x[(r0 + rr) * 128 + c] = xf;
    xns[rr][c] = xf;
  }
  __syncthreads();
  if (MODE == 1) {
    // LN next (t<384)
    if (t < 384) {
      int rr = t >> 7, c = t & 127;
      float xv = xns[rr][c];
      float ps = xv, pq = xv * xv;
#pragma unroll
      for (int o = 1; o < 64; o <<= 1) { ps += __shfl_xor(ps, o); pq += __shfl_xor(pq, o); }
      int wv = t >> 6;
      if ((t & 63) == 0) { red[wv] = ps; red[6 + wv] = pq; }
    }
    __syncthreads();
    if (t < 384) {
      int rr = t >> 7, c = t & 127;
      float xv = xns[rr][c];
      float mean = (red[2 * rr] + red[2 * rr + 1]) * (1.f / 128.f);
      float var = (red[6 + 2 * rr] + red[6 + 2 * rr + 1]) * (1.f / 128.f) - mean * mean;
      float rstd = rsqrtf(var + 1e-5f);
      asr[rr][c] = (xv - mean) * rstd * lng_n[c] + lnb_n[c];
    }
    __syncthreads();
    // qkvg tail (all 512 threads, all 3 rows; cols select matrix)
    {
      int cg4 = (t & 127) * 4, ks = t >> 7;
      int k0 = ks * 32;
      int mtx = cg4 >> 7, lc = cg4 & 127;
      const float* Wm = (mtx == 0) ? Wq : (mtx == 1) ? Wk : (mtx == 2) ? Wv : Wg;
      float a00 = 0.f, a01 = 0.f, a02 = 0.f, a03 = 0.f;
      float a10 = 0.f, a11 = 0.f, a12 = 0.f, a13 = 0.f;
      float a20 = 0.f, a21 = 0.f, a22 = 0.f, a23 = 0.f;
#pragma unroll 8
      for (int kk = 0; kk < 32; kk++) {
        int k = k0 + kk;
        float4 w = *(const float4*)&Wm[k * 128 + lc];
        float v0 = asr[0][k], v1 = asr[1][k], v2 = asr[2][k];
        a00 += v0 * w.x; a01 += v0 * w.y; a02 += v0 * w.z; a03 += v0 * w.w;
        a10 += v1 * w.x; a11 += v1 * w.y; a12 += v1 * w.z; a13 += v1 * w.w;
        a20 += v2 * w.x; a21 += v2 * w.y; a22 += v2 * w.z; a23 += v2 * w.w;
      }
      *(float4*)&part2[ks][0][cg4] = make_float4(a00, a01, a02, a03);
      *(float4*)&part2[ks][1][cg4] = make_float4(a10, a11, a12, a13);
      *(float4*)&part2[ks][2][cg4] = make_float4(a20, a21, a22, a23);
    }
    __syncthreads();
    {
#pragma unroll
      for (int row = 0; row < 3; row++) {
        float v = part2[0][row][t] + part2[1][row][t] + part2[2][row][t] + part2[3][row][t];
        qkvg[(r0 + row) * 512 + t] = v;
      }
    }
  }
  if (MODE == 2) {
    if (t < 384) {
      int tk = blockIdx.x;
      float a0 = 0.f, a1 = 0.f, a2 = 0.f;
#pragma unroll 8
      for (int k = 0; k < 128; k++) {
        float w = W_proj[k * 384 + t];
        a0 += xns[0][k] * w; a1 += xns[1][k] * w; a2 += xns[2][k] * w;
      }
      a0 = fmaxf(a0, 0.f); a1 = fmaxf(a1, 0.f); a2 = fmaxf(a2, 0.f);
      out[98304 + (tk * 3 + 0) * 384 + t] = a0;
      out[98304 + (tk * 3 + 1) * 384 + t] = a1;
      out[98304 + (tk * 3 + 2) * 384 + t] = a2;
      out[tk * 384 + t] = (a0 + a1 + a2) * (1.f / 3.f);
    }
  }
}

// ---------------------------------------------------------------------------
extern "C" void kernel_launch(void* const* d_in, const int* in_sizes, int n_in,
                              void* d_out, int out_size, void* d_ws, size_t ws_size,
                              hipStream_t stream) {
  const float* ref_pos  = (const float*)d_in[0];
  const int*   uid      = (const int*)d_in[1];
  const float* r        = (const float*)d_in[2];
  const float* s        = (const float*)d_in[3];
  const float* z        = (const float*)d_in[4];
  const float* W_pos    = (const float*)d_in[5];
  const float* Wpo      = (const float*)d_in[6];
  const float* Wisd     = (const float*)d_in[7];
  const float* Wmask    = (const float*)d_in[8];
  const float* Wca      = (const float*)d_in[9];
  const float* Wcb      = (const float*)d_in[10];
  const float* ln_s_g   = (const float*)d_in[11];
  const float* ln_s_b   = (const float*)d_in[12];
  const float* W_single = (const float*)d_in[13];
  const float* ln_z_g   = (const float*)d_in[14];
  const float* ln_z_b   = (const float*)d_in[15];
  const float* W_pair   = (const float*)d_in[16];
  const float* W_noisy  = (const float*)d_in[17];
  const float* W_mlp1   = (const float*)d_in[18];
  const float* W_mlp2   = (const float*)d_in[19];
  const float* W_mlp3   = (const float*)d_in[20];
  const float* at_ln_g  = (const float*)d_in[21];
  const float* at_ln_b  = (const float*)d_in[22];
  const float* at_Wq    = (const float*)d_in[23];
  const float* at_Wk    = (const float*)d_in[24];
  const float* at_Wv    = (const float*)d_in[25];
  const float* at_Wg    = (const float*)d_in[26];
  const float* at_lnp_g = (const float*)d_in[27];
  const float* at_lnp_b = (const float*)d_in[28];
  const float* at_Wb    = (const float*)d_in[29];
  const float* at_Wo    = (const float*)d_in[30];
  const float* at_ln2_g = (const float*)d_in[31];
  const float* at_ln2_b = (const float*)d_in[32];
  const float* at_Wt1   = (const float*)d_in[33];
  const float* at_Wt2   = (const float*)d_in[34];
  const float* W_proj   = (const float*)d_in[35];
  float* out = (float*)d_out;
  float* W = (float*)d_ws;
  float* x     = W;                 //   98304
  float* ca    = W + 98304;         //   12288
  float* cb    = W + 110592;        //   12288
  float* zp    = W + 122880;        // 1048576
  float* biasA = W + 1171456;       // 1179648
  float* qkvg  = W + 2351104;       //  393216
  float* og    = W + 2744320;       //   98304

  k_front<<<1280, 256, 0, stream>>>(z, ln_z_g, ln_z_b, W_pair, zp,
                                    s, ln_s_g, ln_s_b, W_single, ref_pos, r,
                                    W_pos, W_noisy, Wca, Wcb,
                                    out + 393216, x, ca, cb);
  k_pairq<<<2688, 256, 0, stream>>>(ref_pos, uid, Wpo, Wisd, Wmask, W_mlp1, W_mlp2,
                                    W_mlp3, zp, ca, cb, at_lnp_g, at_lnp_b, at_Wb,
                                    out + 491520, biasA,
                                    x, at_ln_g, at_ln_b, at_Wq, at_Wk, at_Wv, at_Wg,
                                    qkvg);
  // layer 0
  k_attn2<<<192, 256, 0, stream>>>(qkvg, biasA, og);
  k_fusedT<1><<<256, 512, 0, stream>>>(og, at_Wo, at_ln2_g, at_ln2_b, at_Wt1, at_Wt2, x,
                                       at_ln_g + 128, at_ln_b + 128,
                                       at_Wq + 16384, at_Wk + 16384,
                                       at_Wv + 16384, at_Wg + 16384, qkvg,
                                       nullptr, nullptr);
  // layer 1
  k_attn2<<<192, 256, 0, stream>>>(qkvg, biasA + 393216, og);
  k_fusedT<1><<<256, 512, 0, stream>>>(og, at_Wo + 16384, at_ln2_g + 128, at_ln2_b + 128,
                                       at_Wt1 + 65536, at_Wt2 + 65536, x,
                                       at_ln_g + 256, at_ln_b + 256,
                                       at_Wq + 32768, at_Wk + 32768,
                                       at_Wv + 32768, at_Wg + 32768, qkvg,
                                       nullptr, nullptr);
  // layer 2
  k_attn2<<<192, 256, 0, stream>>>(qkvg, biasA + 786432, og);
  k_fusedT<2><<<256, 512, 0, stream>>>(og, at_Wo + 32768, at_ln2_g + 256, at_ln2_b + 256,
                                       at_Wt1 + 131072, at_Wt2 + 131072, x,
                                       nullptr, nullptr, nullptr, nullptr,
                                       nullptr, nullptr, nullptr, W_proj, out);
}